// Round 1
// baseline (8744.326 us; speedup 1.0000x reference)
//
#include <hip/hip_runtime.h>
#include <math.h>

#define NL   4
#define DIM  256
#define NH   8
#define HDIM 32
#define NB   2
#define SQL  1024
#define SKL  1024
#define FFD  768
#define CB   4              // combined batch: 2 stacks * 2 batch
#define ROWS (CB * SQL)     // 4096

// ---------------------------------------------------------------- utilities

__device__ __forceinline__ float mishf(float x) {
    float sp = (x > 20.0f) ? x : log1pf(expf(x));
    return x * tanhf(sp);
}

// ---------------------------------------------------------------- init

__global__ __launch_bounds__(256) void init_kernel(
        const float* __restrict__ pose, const float* __restrict__ vel,
        const float* __restrict__ img, float* __restrict__ X,
        float* __restrict__ KVIN) {
    int idx = blockIdx.x * 256 + threadIdx.x;
    if (idx >= CB * SQL * DIM) return;
    int c = idx / (SQL * DIM);
    int rem = idx - c * (SQL * DIM);
    int b = c & 1;
    X[idx] = pose[b * SQL * DIM + rem];
    const float* kv = (c < 2) ? vel : img;   // stack0 -> vel (pose_out), stack1 -> img (img_out)
    KVIN[idx] = kv[b * SQL * DIM + rem];
}

// ---------------------------------------------------------------- GEMM
// C[M,N] = act(A[M,K] @ W[K,N] + bias[N]) (+ res[M,N])
// 64x64 tile, BK=16, 256 threads, 4x4 per thread. M%64==0, N%64==0, K%16==0.

__global__ __launch_bounds__(256) void gemm_bias(
        const float* __restrict__ A, const float* __restrict__ W,
        const float* __restrict__ bias, const float* __restrict__ res,
        float* __restrict__ C, int M, int N, int K, int act) {
    __shared__ float As[64][17];
    __shared__ float Ws[16][65];
    int t  = threadIdx.x;
    int tx = t & 15;
    int ty = t >> 4;
    int bm = blockIdx.y * 64;
    int bn = blockIdx.x * 64;

    float acc[4][4];
#pragma unroll
    for (int i = 0; i < 4; i++)
#pragma unroll
        for (int j = 0; j < 4; j++) acc[i][j] = 0.0f;

    for (int k0 = 0; k0 < K; k0 += 16) {
#pragma unroll
        for (int i = 0; i < 4; i++) {
            int idx = t + i * 256;            // 0..1023
            int r = idx >> 4, c = idx & 15;   // 64 x 16
            As[r][c] = A[(size_t)(bm + r) * K + k0 + c];
        }
#pragma unroll
        for (int i = 0; i < 4; i++) {
            int idx = t + i * 256;
            int r = idx >> 6, c = idx & 63;   // 16 x 64
            Ws[r][c] = W[(size_t)(k0 + r) * N + bn + c];
        }
        __syncthreads();
#pragma unroll
        for (int kk = 0; kk < 16; kk++) {
            float a[4], b[4];
#pragma unroll
            for (int i = 0; i < 4; i++) a[i] = As[ty * 4 + i][kk];
#pragma unroll
            for (int j = 0; j < 4; j++) b[j] = Ws[kk][tx * 4 + j];
#pragma unroll
            for (int i = 0; i < 4; i++)
#pragma unroll
                for (int j = 0; j < 4; j++) acc[i][j] += a[i] * b[j];
        }
        __syncthreads();
    }

#pragma unroll
    for (int i = 0; i < 4; i++) {
        int r = bm + ty * 4 + i;
#pragma unroll
        for (int j = 0; j < 4; j++) {
            int c = bn + tx * 4 + j;
            float v = acc[i][j] + bias[c];
            if (act == 1) v = mishf(v);
            if (res) v += res[(size_t)r * N + c];
            C[(size_t)r * N + c] = v;
        }
    }
}

// ---------------------------------------------------------------- LayerNorm
// out[row] = (res ? res[row] : 0) + LN(in[row]) * g + b ; one block per row, D=256.

__global__ __launch_bounds__(256) void ln_kernel(
        const float* __restrict__ in, const float* __restrict__ res,
        const float* __restrict__ g, const float* __restrict__ b,
        float* __restrict__ out) {
    int row = blockIdx.x;
    int t = threadIdx.x;
    float x = in[(size_t)row * DIM + t];
    float s = x, s2 = x * x;
#pragma unroll
    for (int off = 32; off; off >>= 1) {
        s  += __shfl_down(s, off);
        s2 += __shfl_down(s2, off);
    }
    __shared__ float ws[4], ws2[4];
    __shared__ float mean_s, rstd_s;
    int wid = t >> 6, lane = t & 63;
    if (lane == 0) { ws[wid] = s; ws2[wid] = s2; }
    __syncthreads();
    if (t == 0) {
        float S  = ws[0] + ws[1] + ws[2] + ws[3];
        float S2 = ws2[0] + ws2[1] + ws2[2] + ws2[3];
        float m = S * (1.0f / DIM);
        float v = S2 * (1.0f / DIM) - m * m;
        mean_s = m;
        rstd_s = rsqrtf(v + 1e-5f);
    }
    __syncthreads();
    float y = (x - mean_s) * rstd_s * g[t] + b[t];
    if (res) y += res[(size_t)row * DIM + t];
    out[(size_t)row * DIM + t] = y;
}

// ---------------------------------------------------------------- attention
// One block per (c, h, q) row: scores -> entmax1.5 (bisection) -> @V.
// grid: (SQL, NH, CB), 256 threads.

__global__ __launch_bounds__(256) void attn_kernel(
        const float* __restrict__ Q, const float* __restrict__ K,
        const float* __restrict__ V, float* __restrict__ O) {
    int q = blockIdx.x, h = blockIdx.y, c = blockIdx.z;
    int t = threadIdx.x;

    __shared__ float qv[HDIM];
    __shared__ float pbuf[SKL];
    __shared__ float red[4];
    __shared__ float vred[8][32];

    if (t < HDIM) qv[t] = Q[((size_t)(c * SQL + q)) * DIM + h * HDIM + t];
    __syncthreads();

    const float scale = 0.5f * 0.17677669529663687f;  // 0.5 / sqrt(32)

    float x[4];
#pragma unroll
    for (int i = 0; i < 4; i++) {
        int k = t + i * 256;
        const float* kp = &K[((size_t)(c * SKL + k)) * DIM + h * HDIM];
        float s = 0.0f;
#pragma unroll
        for (int d = 0; d < HDIM; d++) s += qv[d] * kp[d];
        x[i] = s * scale;
    }

    // row max
    float m = fmaxf(fmaxf(x[0], x[1]), fmaxf(x[2], x[3]));
#pragma unroll
    for (int off = 32; off; off >>= 1) m = fmaxf(m, __shfl_down(m, off));
    if ((t & 63) == 0) red[t >> 6] = m;
    __syncthreads();
    m = fmaxf(fmaxf(red[0], red[1]), fmaxf(red[2], red[3]));
    __syncthreads();
#pragma unroll
    for (int i = 0; i < 4; i++) x[i] -= m;

    // bisection for tau in [-1, 0]: f(tau) = sum clip(x - tau, 0)^2, f(tau*) = 1
    float lo = -1.0f, hi = 0.0f;
    for (int it = 0; it < 30; it++) {
        float tau = 0.5f * (lo + hi);
        float f = 0.0f;
#pragma unroll
        for (int i = 0; i < 4; i++) {
            float d = x[i] - tau;
            if (d > 0.0f) f += d * d;
        }
#pragma unroll
        for (int off = 32; off; off >>= 1) f += __shfl_down(f, off);
        if ((t & 63) == 0) red[t >> 6] = f;
        __syncthreads();
        f = red[0] + red[1] + red[2] + red[3];
        __syncthreads();
        if (f >= 1.0f) lo = tau; else hi = tau;
    }
    float tau = 0.5f * (lo + hi);
#pragma unroll
    for (int i = 0; i < 4; i++) {
        float d = x[i] - tau;
        pbuf[t + i * 256] = (d > 0.0f) ? d * d : 0.0f;
    }
    __syncthreads();

    // out[d] = sum_k p[k] * V[k, d] ; 8 groups of 32 lanes
    int d = t & 31, grp = t >> 5;
    float acc = 0.0f;
    for (int k = grp; k < SKL; k += 8)
        acc += pbuf[k] * V[((size_t)(c * SKL + k)) * DIM + h * HDIM + d];
    vred[grp][d] = acc;
    __syncthreads();
    if (t < 32) {
        float o = 0.0f;
#pragma unroll
        for (int gg = 0; gg < 8; gg++) o += vred[gg][t];
        O[((size_t)(c * SQL + q)) * DIM + h * HDIM + t] = o;
    }
}

// ---------------------------------------------------------------- driver

extern "C" void kernel_launch(void* const* d_in, const int* in_sizes, int n_in,
                              void* d_out, int out_size, void* d_ws, size_t ws_size,
                              hipStream_t stream) {
    const float* pose = (const float*)d_in[0];
    const float* vel  = (const float*)d_in[1];
    const float* img  = (const float*)d_in[2];
    const float* Wq   = (const float*)d_in[3];
    const float* bq   = (const float*)d_in[4];
    const float* Wk   = (const float*)d_in[5];
    const float* bk   = (const float*)d_in[6];
    const float* Wv   = (const float*)d_in[7];
    const float* bv   = (const float*)d_in[8];
    const float* Wo   = (const float*)d_in[9];
    const float* bo   = (const float*)d_in[10];
    const float* an_g = (const float*)d_in[11];
    const float* an_b = (const float*)d_in[12];
    const float* W1   = (const float*)d_in[13];
    const float* b1   = (const float*)d_in[14];
    const float* W2   = (const float*)d_in[15];
    const float* b2   = (const float*)d_in[16];
    const float* fn_g = (const float*)d_in[17];
    const float* fn_b = (const float*)d_in[18];
    const float* n_g  = (const float*)d_in[19];
    const float* n_b  = (const float*)d_in[20];

    float* ws = (float*)d_ws;
    const size_t SZ = (size_t)ROWS * DIM;       // 1M floats
    float* X    = ws;                           // [CB][SQ][D] current stream
    float* KVIN = X + SZ;                       // [CB][SK][D] kv input per stack
    float* T1   = KVIN + SZ;
    float* T2   = T1 + SZ;
    float* X1b  = T2 + SZ;
    float* Qb   = X1b + SZ;                     // Q / later FF (12MB region starts here)
    float* Kb   = Qb + SZ;
    float* Vb   = Kb + SZ;
    float* FFb  = Qb;                           // [CB][SQ][FFD] aliases Q/K/V (free by then)

    // init X (pose broadcast to both stacks) and KVIN (vel, img)
    {
        int total = CB * SQL * DIM;
        init_kernel<<<(total + 255) / 256, 256, 0, stream>>>(pose, vel, img, X, KVIN);
    }

    dim3 g_d(DIM / 64, ROWS / 64);    // N=256
    dim3 g_ff(FFD / 64, ROWS / 64);   // N=768
    dim3 g_attn(SQL, NH, CB);

    for (int i = 0; i < NL; i++) {
        const float* Wq_i = Wq + (size_t)i * DIM * DIM;
        const float* Wk_i = Wk + (size_t)i * DIM * DIM;
        const float* Wv_i = Wv + (size_t)i * DIM * DIM;
        const float* Wo_i = Wo + (size_t)i * DIM * DIM;
        const float* W1_i = W1 + (size_t)i * DIM * FFD;
        const float* W2_i = W2 + (size_t)i * FFD * DIM;

        // projections
        gemm_bias<<<g_d, 256, 0, stream>>>(X,    Wq_i, bq + i * DIM, nullptr, Qb, ROWS, DIM, DIM, 0);
        gemm_bias<<<g_d, 256, 0, stream>>>(KVIN, Wk_i, bk + i * DIM, nullptr, Kb, ROWS, DIM, DIM, 0);
        gemm_bias<<<g_d, 256, 0, stream>>>(KVIN, Wv_i, bv + i * DIM, nullptr, Vb, ROWS, DIM, DIM, 0);

        // fused entmax attention -> T1
        attn_kernel<<<g_attn, 256, 0, stream>>>(Qb, Kb, Vb, T1);

        // out projection -> T2
        gemm_bias<<<g_d, 256, 0, stream>>>(T1, Wo_i, bo + i * DIM, nullptr, T2, ROWS, DIM, DIM, 0);

        // x1 = x + LN(T2)
        ln_kernel<<<ROWS, 256, 0, stream>>>(T2, X, an_g + i * DIM, an_b + i * DIM, X1b);

        // y = LN(x1) -> T1
        ln_kernel<<<ROWS, 256, 0, stream>>>(X1b, nullptr, fn_g + i * DIM, fn_b + i * DIM, T1);

        // FF = mish(y @ W1 + b1)   (overwrites Q/K/V region)
        gemm_bias<<<g_ff, 256, 0, stream>>>(T1, W1_i, b1 + i * FFD, nullptr, FFb, ROWS, FFD, DIM, 1);

        // x2 = x1 + FF @ W2 + b2 -> T2
        gemm_bias<<<g_d, 256, 0, stream>>>(FFb, W2_i, b2 + i * DIM, X1b, T2, ROWS, DIM, FFD, 0);

        // x = mem + LN(x2); last layer writes straight to d_out
        float* outp = (i == NL - 1) ? (float*)d_out : X;
        ln_kernel<<<ROWS, 256, 0, stream>>>(T2, X, n_g + i * DIM, n_b + i * DIM, outp);
    }

    (void)in_sizes; (void)n_in; (void)out_size; (void)ws_size;
}

// Round 2
// 1902.024 us; speedup vs baseline: 4.5974x; 4.5974x over previous
//
#include <hip/hip_runtime.h>
#include <math.h>

#define NL   4
#define DIM  256
#define NH   8
#define HDIM 32
#define SQL  1024
#define SKL  1024
#define FFD  768
#define CB   4              // combined batch: 2 stacks * 2 batch
#define ROWS (CB * SQL)     // 4096
#define QW   2              // q rows per wave
#define WPB  4              // waves per block
#define QPB  (QW * WPB)     // 8 q rows per block

// ---------------------------------------------------------------- utilities

__device__ __forceinline__ float mishf(float x) {
    float sp = (x > 20.0f) ? x : log1pf(expf(x));
    return x * tanhf(sp);
}

// ---------------------------------------------------------------- init

__global__ __launch_bounds__(256) void init_kernel(
        const float* __restrict__ pose, const float* __restrict__ vel,
        const float* __restrict__ img, float* __restrict__ X,
        float* __restrict__ KVIN) {
    int idx = blockIdx.x * 256 + threadIdx.x;
    if (idx >= CB * SQL * DIM) return;
    int c = idx / (SQL * DIM);
    int rem = idx - c * (SQL * DIM);
    int b = c & 1;
    X[idx] = pose[b * SQL * DIM + rem];
    const float* kv = (c < 2) ? vel : img;   // stack0 -> vel (pose_out), stack1 -> img (img_out)
    KVIN[idx] = kv[b * SQL * DIM + rem];
}

// ---------------------------------------------------------------- GEMM
// C[M,N] = act(A[M,K] @ W[K,N] + bias[N]) (+ res[M,N])

__global__ __launch_bounds__(256) void gemm_bias(
        const float* __restrict__ A, const float* __restrict__ W,
        const float* __restrict__ bias, const float* __restrict__ res,
        float* __restrict__ C, int M, int N, int K, int act) {
    __shared__ float As[64][17];
    __shared__ float Ws[16][65];
    int t  = threadIdx.x;
    int tx = t & 15;
    int ty = t >> 4;
    int bm = blockIdx.y * 64;
    int bn = blockIdx.x * 64;

    float acc[4][4];
#pragma unroll
    for (int i = 0; i < 4; i++)
#pragma unroll
        for (int j = 0; j < 4; j++) acc[i][j] = 0.0f;

    for (int k0 = 0; k0 < K; k0 += 16) {
#pragma unroll
        for (int i = 0; i < 4; i++) {
            int idx = t + i * 256;
            int r = idx >> 4, c = idx & 15;
            As[r][c] = A[(size_t)(bm + r) * K + k0 + c];
        }
#pragma unroll
        for (int i = 0; i < 4; i++) {
            int idx = t + i * 256;
            int r = idx >> 6, c = idx & 63;
            Ws[r][c] = W[(size_t)(k0 + r) * N + bn + c];
        }
        __syncthreads();
#pragma unroll
        for (int kk = 0; kk < 16; kk++) {
            float a[4], b[4];
#pragma unroll
            for (int i = 0; i < 4; i++) a[i] = As[ty * 4 + i][kk];
#pragma unroll
            for (int j = 0; j < 4; j++) b[j] = Ws[kk][tx * 4 + j];
#pragma unroll
            for (int i = 0; i < 4; i++)
#pragma unroll
                for (int j = 0; j < 4; j++) acc[i][j] += a[i] * b[j];
        }
        __syncthreads();
    }

#pragma unroll
    for (int i = 0; i < 4; i++) {
        int r = bm + ty * 4 + i;
#pragma unroll
        for (int j = 0; j < 4; j++) {
            int c = bn + tx * 4 + j;
            float v = acc[i][j] + bias[c];
            if (act == 1) v = mishf(v);
            if (res) v += res[(size_t)r * N + c];
            C[(size_t)r * N + c] = v;
        }
    }
}

// ---------------------------------------------------------------- LayerNorm

__global__ __launch_bounds__(256) void ln_kernel(
        const float* __restrict__ in, const float* __restrict__ res,
        const float* __restrict__ g, const float* __restrict__ b,
        float* __restrict__ out) {
    int row = blockIdx.x;
    int t = threadIdx.x;
    float x = in[(size_t)row * DIM + t];
    float s = x, s2 = x * x;
#pragma unroll
    for (int off = 32; off; off >>= 1) {
        s  += __shfl_down(s, off);
        s2 += __shfl_down(s2, off);
    }
    __shared__ float ws[4], ws2[4];
    __shared__ float mean_s, rstd_s;
    int wid = t >> 6, lane = t & 63;
    if (lane == 0) { ws[wid] = s; ws2[wid] = s2; }
    __syncthreads();
    if (t == 0) {
        float S  = ws[0] + ws[1] + ws[2] + ws[3];
        float S2 = ws2[0] + ws2[1] + ws2[2] + ws2[3];
        float m = S * (1.0f / DIM);
        float v = S2 * (1.0f / DIM) - m * m;
        mean_s = m;
        rstd_s = rsqrtf(v + 1e-5f);
    }
    __syncthreads();
    float y = (x - mean_s) * rstd_s * g[t] + b[t];
    if (res) y += res[(size_t)row * DIM + t];
    out[(size_t)row * DIM + t] = y;
}

// ---------------------------------------------------------------- attention
// Block = 4 waves; each wave owns QW=2 q rows of head (c,h). K/V staged in
// LDS chunks of 128 rows. Entmax-1.5 fully wave-local: 14 bisection iters to
// bracket tau, then 2 closed-form support refinements (exact quadratic solve).
// grid: (SQL/QPB, NH, CB), 256 threads.

__global__ __launch_bounds__(256) void attn_kernel(
        const float* __restrict__ Q, const float* __restrict__ K,
        const float* __restrict__ V, float* __restrict__ O) {
    int h = blockIdx.y, c = blockIdx.z;
    int qbase = blockIdx.x * QPB;
    int t = threadIdx.x;
    int l = t & 63, w = t >> 6;

    __shared__ float  kvbuf[128][33];      // 16.9 KB, 2-way bank access (free)
    __shared__ float2 pbuf[WPB][SKL];      // 32 KB, p for both q rows packed

    // q rows of this wave -> registers (wave-uniform loads, L2/L1 hit)
    float qreg[QW][HDIM];
#pragma unroll
    for (int qq = 0; qq < QW; qq++) {
        const float* qp = Q + ((size_t)(c * SQL + qbase + w * QW + qq)) * DIM + h * HDIM;
#pragma unroll
        for (int d = 0; d < HDIM; d += 4) {
            float4 v4 = *reinterpret_cast<const float4*>(qp + d);
            qreg[qq][d] = v4.x; qreg[qq][d + 1] = v4.y;
            qreg[qq][d + 2] = v4.z; qreg[qq][d + 3] = v4.w;
        }
    }

    const float scale = 0.08838834764831845f;   // 0.5 / sqrt(32)
    float x[QW][16];                            // scores: x[qq][j] for k = j*64 + l

    int sr = t >> 1;                            // staging: 2 threads per row
    int sd = (t & 1) << 4;

    // ---- scores: x = 0.5 * (q . k) / sqrt(hd)
#pragma unroll
    for (int ck = 0; ck < 8; ck++) {
        const float* src = K + ((size_t)(c * SKL + ck * 128 + sr)) * DIM + h * HDIM + sd;
#pragma unroll
        for (int i = 0; i < 16; i += 4) {
            float4 v4 = *reinterpret_cast<const float4*>(src + i);
            kvbuf[sr][sd + i]     = v4.x; kvbuf[sr][sd + i + 1] = v4.y;
            kvbuf[sr][sd + i + 2] = v4.z; kvbuf[sr][sd + i + 3] = v4.w;
        }
        __syncthreads();
#pragma unroll
        for (int jj = 0; jj < 2; jj++) {
            int lr = jj * 64 + l;
            float s0 = 0.f, s1 = 0.f;
#pragma unroll
            for (int d = 0; d < HDIM; d++) {
                float kv = kvbuf[lr][d];
                s0 += qreg[0][d] * kv;
                s1 += qreg[1][d] * kv;
            }
            x[0][ck * 2 + jj] = s0 * scale;
            x[1][ck * 2 + jj] = s1 * scale;
        }
        __syncthreads();
    }

    // ---- entmax 1.5, wave-local. tau* in [-1, -1/32] (f <= 1024*tau^2).
    float tau[QW], lov[QW], hiv[QW];
#pragma unroll
    for (int qq = 0; qq < QW; qq++) {
        float m = x[qq][0];
#pragma unroll
        for (int j = 1; j < 16; j++) m = fmaxf(m, x[qq][j]);
#pragma unroll
        for (int off = 1; off < 64; off <<= 1) m = fmaxf(m, __shfl_xor(m, off));
#pragma unroll
        for (int j = 0; j < 16; j++) x[qq][j] -= m;
        lov[qq] = -1.0f;
        hiv[qq] = -0.03125f;
    }

#pragma unroll 1
    for (int it = 0; it < 14; it++) {
        float f[QW], tm[QW];
#pragma unroll
        for (int qq = 0; qq < QW; qq++) {
            tm[qq] = 0.5f * (lov[qq] + hiv[qq]);
            float s = 0.f;
#pragma unroll
            for (int j = 0; j < 16; j++) {
                float dd = fmaxf(x[qq][j] - tm[qq], 0.f);
                s += dd * dd;
            }
            f[qq] = s;
        }
#pragma unroll
        for (int off = 1; off < 64; off <<= 1) {
            f[0] += __shfl_xor(f[0], off);
            f[1] += __shfl_xor(f[1], off);
        }
#pragma unroll
        for (int qq = 0; qq < QW; qq++) {
            if (f[qq] >= 1.0f) lov[qq] = tm[qq]; else hiv[qq] = tm[qq];
        }
    }
#pragma unroll
    for (int qq = 0; qq < QW; qq++) tau[qq] = 0.5f * (lov[qq] + hiv[qq]);

    // closed-form refinement: with support S = {x > tau}, solve
    // n*t^2 - 2*S1*t + (S2 - 1) = 0 -> t = (S1 - sqrt(S1^2 - n*(S2-1)))/n
#pragma unroll 1
    for (int r = 0; r < 2; r++) {
#pragma unroll
        for (int qq = 0; qq < QW; qq++) {
            float n = 0.f, s1 = 0.f, s2 = 0.f;
#pragma unroll
            for (int j = 0; j < 16; j++) {
                float xv = x[qq][j];
                if (xv > tau[qq]) { n += 1.f; s1 += xv; s2 += xv * xv; }
            }
#pragma unroll
            for (int off = 1; off < 64; off <<= 1) {
                n  += __shfl_xor(n, off);
                s1 += __shfl_xor(s1, off);
                s2 += __shfl_xor(s2, off);
            }
            float disc = fmaxf(s1 * s1 - n * (s2 - 1.0f), 0.f);
            float tn = (s1 - sqrtf(disc)) / n;
            tau[qq] = fminf(fmaxf(tn, -1.0f), -0.03125f);
        }
    }

    // ---- p = clip(x - tau)^2, packed float2 for the wave's two q rows
#pragma unroll
    for (int j = 0; j < 16; j++) {
        float d0 = fmaxf(x[0][j] - tau[0], 0.f);
        float d1 = fmaxf(x[1][j] - tau[1], 0.f);
        pbuf[w][j * 64 + l] = make_float2(d0 * d0, d1 * d1);
    }
    __syncthreads();

    // ---- PV: out[qq][d] = sum_k p[qq][k] * V[k][d]
    int dd = l & 31, hh = l >> 5;
    float acc0 = 0.f, acc1 = 0.f;
#pragma unroll 1
    for (int ck = 0; ck < 8; ck++) {
        const float* src = V + ((size_t)(c * SKL + ck * 128 + sr)) * DIM + h * HDIM + sd;
#pragma unroll
        for (int i = 0; i < 16; i += 4) {
            float4 v4 = *reinterpret_cast<const float4*>(src + i);
            kvbuf[sr][sd + i]     = v4.x; kvbuf[sr][sd + i + 1] = v4.y;
            kvbuf[sr][sd + i + 2] = v4.z; kvbuf[sr][sd + i + 3] = v4.w;
        }
        __syncthreads();
#pragma unroll 8
        for (int i = 0; i < 64; i++) {
            int kl = 2 * i + hh;
            float vv = kvbuf[kl][dd];
            float2 pp = pbuf[w][ck * 128 + kl];
            acc0 += pp.x * vv;
            acc1 += pp.y * vv;
        }
        __syncthreads();
    }
    acc0 += __shfl_down(acc0, 32);
    acc1 += __shfl_down(acc1, 32);
    if (l < 32) {
        size_t r0 = ((size_t)(c * SQL + qbase + w * QW + 0)) * DIM + h * HDIM + dd;
        size_t r1 = ((size_t)(c * SQL + qbase + w * QW + 1)) * DIM + h * HDIM + dd;
        O[r0] = acc0;
        O[r1] = acc1;
    }
}

// ---------------------------------------------------------------- driver

extern "C" void kernel_launch(void* const* d_in, const int* in_sizes, int n_in,
                              void* d_out, int out_size, void* d_ws, size_t ws_size,
                              hipStream_t stream) {
    const float* pose = (const float*)d_in[0];
    const float* vel  = (const float*)d_in[1];
    const float* img  = (const float*)d_in[2];
    const float* Wq   = (const float*)d_in[3];
    const float* bq   = (const float*)d_in[4];
    const float* Wk   = (const float*)d_in[5];
    const float* bk   = (const float*)d_in[6];
    const float* Wv   = (const float*)d_in[7];
    const float* bv   = (const float*)d_in[8];
    const float* Wo   = (const float*)d_in[9];
    const float* bo   = (const float*)d_in[10];
    const float* an_g = (const float*)d_in[11];
    const float* an_b = (const float*)d_in[12];
    const float* W1   = (const float*)d_in[13];
    const float* b1   = (const float*)d_in[14];
    const float* W2   = (const float*)d_in[15];
    const float* b2   = (const float*)d_in[16];
    const float* fn_g = (const float*)d_in[17];
    const float* fn_b = (const float*)d_in[18];
    const float* n_g  = (const float*)d_in[19];
    const float* n_b  = (const float*)d_in[20];

    float* ws = (float*)d_ws;
    const size_t SZ = (size_t)ROWS * DIM;       // 1M floats
    float* X    = ws;
    float* KVIN = X + SZ;
    float* T1   = KVIN + SZ;
    float* T2   = T1 + SZ;
    float* X1b  = T2 + SZ;
    float* Qb   = X1b + SZ;
    float* Kb   = Qb + SZ;
    float* Vb   = Kb + SZ;
    float* FFb  = Qb;                           // aliases Q/K/V (free by then)

    {
        int total = CB * SQL * DIM;
        init_kernel<<<(total + 255) / 256, 256, 0, stream>>>(pose, vel, img, X, KVIN);
    }

    dim3 g_d(DIM / 64, ROWS / 64);
    dim3 g_ff(FFD / 64, ROWS / 64);
    dim3 g_attn(SQL / QPB, NH, CB);

    for (int i = 0; i < NL; i++) {
        const float* Wq_i = Wq + (size_t)i * DIM * DIM;
        const float* Wk_i = Wk + (size_t)i * DIM * DIM;
        const float* Wv_i = Wv + (size_t)i * DIM * DIM;
        const float* Wo_i = Wo + (size_t)i * DIM * DIM;
        const float* W1_i = W1 + (size_t)i * DIM * FFD;
        const float* W2_i = W2 + (size_t)i * FFD * DIM;

        gemm_bias<<<g_d, 256, 0, stream>>>(X,    Wq_i, bq + i * DIM, nullptr, Qb, ROWS, DIM, DIM, 0);
        gemm_bias<<<g_d, 256, 0, stream>>>(KVIN, Wk_i, bk + i * DIM, nullptr, Kb, ROWS, DIM, DIM, 0);
        gemm_bias<<<g_d, 256, 0, stream>>>(KVIN, Wv_i, bv + i * DIM, nullptr, Vb, ROWS, DIM, DIM, 0);

        attn_kernel<<<g_attn, 256, 0, stream>>>(Qb, Kb, Vb, T1);

        gemm_bias<<<g_d, 256, 0, stream>>>(T1, Wo_i, bo + i * DIM, nullptr, T2, ROWS, DIM, DIM, 0);

        ln_kernel<<<ROWS, 256, 0, stream>>>(T2, X, an_g + i * DIM, an_b + i * DIM, X1b);
        ln_kernel<<<ROWS, 256, 0, stream>>>(X1b, nullptr, fn_g + i * DIM, fn_b + i * DIM, T1);

        gemm_bias<<<g_ff, 256, 0, stream>>>(T1, W1_i, b1 + i * FFD, nullptr, FFb, ROWS, FFD, DIM, 1);
        gemm_bias<<<g_d, 256, 0, stream>>>(FFb, W2_i, b2 + i * DIM, X1b, T2, ROWS, DIM, FFD, 0);

        float* outp = (i == NL - 1) ? (float*)d_out : X;
        ln_kernel<<<ROWS, 256, 0, stream>>>(T2, X, n_g + i * DIM, n_b + i * DIM, outp);
    }

    (void)in_sizes; (void)n_in; (void)out_size; (void)ws_size;
}

// Round 3
// 1144.866 us; speedup vs baseline: 7.6379x; 1.6613x over previous
//
#include <hip/hip_runtime.h>
#include <math.h>

#define NL   4
#define DIM  256
#define NH   8
#define HDIM 32
#define SQL  1024
#define SKL  1024
#define FFD  768
#define CB   4              // combined batch: 2 stacks * 2 batch
#define ROWS (CB * SQL)     // 4096

typedef __attribute__((ext_vector_type(8))) short bf16x8;
typedef __attribute__((ext_vector_type(4))) float f32x4;

// ---------------------------------------------------------------- utilities

__device__ __forceinline__ float mishf(float x) {
    float sp = (x > 20.0f) ? x : log1pf(expf(x));
    return x * tanhf(sp);
}

__device__ __forceinline__ short f2bf(float f) {
    union { float f; unsigned u; } v; v.f = f;
    unsigned u = v.u + 0x7fffu + ((v.u >> 16) & 1u);   // RNE
    return (short)(u >> 16);
}

// ---------------------------------------------------------------- init

__global__ __launch_bounds__(256) void init_kernel(
        const float* __restrict__ pose, const float* __restrict__ vel,
        const float* __restrict__ img, float* __restrict__ X,
        float* __restrict__ KVIN) {
    int idx = blockIdx.x * 256 + threadIdx.x;
    if (idx >= CB * SQL * DIM) return;
    int c = idx / (SQL * DIM);
    int rem = idx - c * (SQL * DIM);
    int b = c & 1;
    X[idx] = pose[b * SQL * DIM + rem];
    const float* kv = (c < 2) ? vel : img;   // stack0 -> vel (pose_out), stack1 -> img (img_out)
    KVIN[idx] = kv[b * SQL * DIM + rem];
}

// ---------------------------------------------------------------- GEMM (fp32, unchanged)

__global__ __launch_bounds__(256) void gemm_bias(
        const float* __restrict__ A, const float* __restrict__ W,
        const float* __restrict__ bias, const float* __restrict__ res,
        float* __restrict__ C, int M, int N, int K, int act) {
    __shared__ float As[64][17];
    __shared__ float Ws[16][65];
    int t  = threadIdx.x;
    int tx = t & 15;
    int ty = t >> 4;
    int bm = blockIdx.y * 64;
    int bn = blockIdx.x * 64;

    float acc[4][4];
#pragma unroll
    for (int i = 0; i < 4; i++)
#pragma unroll
        for (int j = 0; j < 4; j++) acc[i][j] = 0.0f;

    for (int k0 = 0; k0 < K; k0 += 16) {
#pragma unroll
        for (int i = 0; i < 4; i++) {
            int idx = t + i * 256;
            int r = idx >> 4, c = idx & 15;
            As[r][c] = A[(size_t)(bm + r) * K + k0 + c];
        }
#pragma unroll
        for (int i = 0; i < 4; i++) {
            int idx = t + i * 256;
            int r = idx >> 6, c = idx & 63;
            Ws[r][c] = W[(size_t)(k0 + r) * N + bn + c];
        }
        __syncthreads();
#pragma unroll
        for (int kk = 0; kk < 16; kk++) {
            float a[4], b[4];
#pragma unroll
            for (int i = 0; i < 4; i++) a[i] = As[ty * 4 + i][kk];
#pragma unroll
            for (int j = 0; j < 4; j++) b[j] = Ws[kk][tx * 4 + j];
#pragma unroll
            for (int i = 0; i < 4; i++)
#pragma unroll
                for (int j = 0; j < 4; j++) acc[i][j] += a[i] * b[j];
        }
        __syncthreads();
    }

#pragma unroll
    for (int i = 0; i < 4; i++) {
        int r = bm + ty * 4 + i;
#pragma unroll
        for (int j = 0; j < 4; j++) {
            int c = bn + tx * 4 + j;
            float v = acc[i][j] + bias[c];
            if (act == 1) v = mishf(v);
            if (res) v += res[(size_t)r * N + c];
            C[(size_t)r * N + c] = v;
        }
    }
}

// ---------------------------------------------------------------- LayerNorm

__global__ __launch_bounds__(256) void ln_kernel(
        const float* __restrict__ in, const float* __restrict__ res,
        const float* __restrict__ g, const float* __restrict__ b,
        float* __restrict__ out) {
    int row = blockIdx.x;
    int t = threadIdx.x;
    float x = in[(size_t)row * DIM + t];
    float s = x, s2 = x * x;
#pragma unroll
    for (int off = 32; off; off >>= 1) {
        s  += __shfl_down(s, off);
        s2 += __shfl_down(s2, off);
    }
    __shared__ float ws[4], ws2[4];
    __shared__ float mean_s, rstd_s;
    int wid = t >> 6, lane = t & 63;
    if (lane == 0) { ws[wid] = s; ws2[wid] = s2; }
    __syncthreads();
    if (t == 0) {
        float S  = ws[0] + ws[1] + ws[2] + ws[3];
        float S2 = ws2[0] + ws2[1] + ws2[2] + ws2[3];
        float m = S * (1.0f / DIM);
        float v = S2 * (1.0f / DIM) - m * m;
        mean_s = m;
        rstd_s = rsqrtf(v + 1e-5f);
    }
    __syncthreads();
    float y = (x - mean_s) * rstd_s * g[t] + b[t];
    if (res) y += res[(size_t)row * DIM + t];
    out[(size_t)row * DIM + t] = y;
}

// ---------------------------------------------------------------- attention (MFMA)
// Block: 4 waves, 16 q rows (head h, batch c). Wave w covers k in [256w,256w+256).
// QK^T via mfma(K_tile, Q^T) so each lane holds one q-row's scores (k spread
// across 16 k-tiles x 4 regs). Entmax-1.5: wave shfl + tiny cross-wave LDS
// reduce. p -> bf16 into swizzled LDS, PV via mfma(P, V). Cross-wave O reduce.
// grid: (SQL/16, NH, CB), 256 threads.

__global__ __launch_bounds__(256) void attn_mfma(
        const float* __restrict__ Q, const float* __restrict__ K,
        const float* __restrict__ V, float* __restrict__ O) {
    int h = blockIdx.y, c = blockIdx.z;
    int qbase = blockIdx.x * 16;
    int t = threadIdx.x, l = t & 63, w = t >> 6;
    int lq = l & 15, lg = l >> 4;

    __shared__ __align__(16) short p_lds[16 * 1024];   // [q][k] bf16, XOR-swizzled, 32KB
    __shared__ float redf[3][4][16];
    float* obuf = (float*)p_lds;                       // aliased after barrier: [4][16][32] f32

    const float scale = 0.08838834764831845f;          // 0.5 / sqrt(32)

    // ---- Q frag (B operand of mfma(K,Q)): lane supplies Q[qbase+lq][8*lg + j], pre-scaled
    bf16x8 qfrag;
    {
        const float* qp = Q + ((size_t)(c * SQL + qbase + lq)) * DIM + h * HDIM + lg * 8;
        float4 x0 = *(const float4*)qp;
        float4 x1 = *(const float4*)(qp + 4);
        qfrag[0] = f2bf(x0.x * scale); qfrag[1] = f2bf(x0.y * scale);
        qfrag[2] = f2bf(x0.z * scale); qfrag[3] = f2bf(x0.w * scale);
        qfrag[4] = f2bf(x1.x * scale); qfrag[5] = f2bf(x1.y * scale);
        qfrag[6] = f2bf(x1.z * scale); qfrag[7] = f2bf(x1.w * scale);
    }

    // ---- QK^T: 16 k-tiles of 16 rows. acc[kt][j] = S[k = 256w+16kt+4lg+j][q=lq]
    const int kw = w * 256;
    f32x4 acc[16];
#pragma unroll
    for (int kt = 0; kt < 16; kt++) {
        const float* kp = K + ((size_t)(c * SKL + kw + kt * 16 + lq)) * DIM + h * HDIM + lg * 8;
        float4 x0 = *(const float4*)kp;
        float4 x1 = *(const float4*)(kp + 4);
        bf16x8 kf;
        kf[0] = f2bf(x0.x); kf[1] = f2bf(x0.y); kf[2] = f2bf(x0.z); kf[3] = f2bf(x0.w);
        kf[4] = f2bf(x1.x); kf[5] = f2bf(x1.y); kf[6] = f2bf(x1.z); kf[7] = f2bf(x1.w);
        f32x4 z = {0.f, 0.f, 0.f, 0.f};
        acc[kt] = __builtin_amdgcn_mfma_f32_16x16x32_bf16(kf, qfrag, z, 0, 0, 0);
    }

    // ---- row max, shift
    float m = acc[0][0];
#pragma unroll
    for (int kt = 0; kt < 16; kt++)
#pragma unroll
        for (int j = 0; j < 4; j++) m = fmaxf(m, acc[kt][j]);
    m = fmaxf(m, __shfl_xor(m, 16));
    m = fmaxf(m, __shfl_xor(m, 32));
    if (l < 16) redf[0][w][l] = m;
    __syncthreads();
    m = fmaxf(fmaxf(redf[0][0][lq], redf[0][1][lq]),
              fmaxf(redf[0][2][lq], redf[0][3][lq]));
#pragma unroll
    for (int kt = 0; kt < 16; kt++)
#pragma unroll
        for (int j = 0; j < 4; j++) acc[kt][j] -= m;

    // ---- bisection: f(tau) = sum clip(x-tau)^2 = 1, tau* in [-1, -1/32]
    float lo = -1.0f, hi = -0.03125f;
#pragma unroll 1
    for (int it = 0; it < 12; it++) {
        float tau = 0.5f * (lo + hi);
        float f = 0.f;
#pragma unroll
        for (int kt = 0; kt < 16; kt++)
#pragma unroll
            for (int j = 0; j < 4; j++) {
                float d = fmaxf(acc[kt][j] - tau, 0.f);
                f += d * d;
            }
        f += __shfl_xor(f, 16);
        f += __shfl_xor(f, 32);
        __syncthreads();
        if (l < 16) redf[0][w][l] = f;
        __syncthreads();
        f = redf[0][0][lq] + redf[0][1][lq] + redf[0][2][lq] + redf[0][3][lq];
        if (f >= 1.0f) lo = tau; else hi = tau;
    }
    float tau = 0.5f * (lo + hi);

    // ---- 2 closed-form support refinements (exact quadratic solve on support)
#pragma unroll 1
    for (int r = 0; r < 2; r++) {
        float n = 0.f, s1 = 0.f, s2 = 0.f;
#pragma unroll
        for (int kt = 0; kt < 16; kt++)
#pragma unroll
            for (int j = 0; j < 4; j++) {
                float xv = acc[kt][j];
                if (xv > tau) { n += 1.f; s1 += xv; s2 += xv * xv; }
            }
        n  += __shfl_xor(n, 16);  n  += __shfl_xor(n, 32);
        s1 += __shfl_xor(s1, 16); s1 += __shfl_xor(s1, 32);
        s2 += __shfl_xor(s2, 16); s2 += __shfl_xor(s2, 32);
        __syncthreads();
        if (l < 16) { redf[0][w][l] = n; redf[1][w][l] = s1; redf[2][w][l] = s2; }
        __syncthreads();
        n  = redf[0][0][lq] + redf[0][1][lq] + redf[0][2][lq] + redf[0][3][lq];
        s1 = redf[1][0][lq] + redf[1][1][lq] + redf[1][2][lq] + redf[1][3][lq];
        s2 = redf[2][0][lq] + redf[2][1][lq] + redf[2][2][lq] + redf[2][3][lq];
        float disc = fmaxf(s1 * s1 - n * (s2 - 1.0f), 0.f);
        tau = fminf(fmaxf((s1 - sqrtf(disc)) / n, -1.0f), -0.03125f);
    }

    // ---- p = clip(x-tau)^2 -> bf16 -> swizzled LDS [q=lq][k], byte ^= lq<<4
#pragma unroll
    for (int kt = 0; kt < 16; kt++) {
        float d0 = fmaxf(acc[kt][0] - tau, 0.f);
        float d1 = fmaxf(acc[kt][1] - tau, 0.f);
        float d2 = fmaxf(acc[kt][2] - tau, 0.f);
        float d3 = fmaxf(acc[kt][3] - tau, 0.f);
        unsigned p01 = (unsigned short)f2bf(d0 * d0) | ((unsigned)(unsigned short)f2bf(d1 * d1) << 16);
        unsigned p23 = (unsigned short)f2bf(d2 * d2) | ((unsigned)(unsigned short)f2bf(d3 * d3) << 16);
        int k = kw + kt * 16 + lg * 4;
        int byte = lq * 2048 + ((k * 2) ^ (lq << 4));
        *(uint2*)((char*)p_lds + byte) = make_uint2(p01, p23);
    }
    __syncthreads();

    // ---- PV: O[q][d] = sum_k P[q][k] V[k][d]; wave sums its k-quarter
    f32x4 o0 = {0.f, 0.f, 0.f, 0.f}, o1 = {0.f, 0.f, 0.f, 0.f};
#pragma unroll
    for (int kt2 = 0; kt2 < 8; kt2++) {
        int k0 = kw + kt2 * 32 + lg * 8;
        int byte = lq * 2048 + ((k0 * 2) ^ (lq << 4));
        bf16x8 pa = *(const bf16x8*)((const char*)p_lds + byte);
        const float* vp = V + ((size_t)(c * SKL + k0)) * DIM + h * HDIM + lq;
        bf16x8 vb0, vb1;
#pragma unroll
        for (int j = 0; j < 8; j++) {
            vb0[j] = f2bf(vp[(size_t)j * DIM]);
            vb1[j] = f2bf(vp[(size_t)j * DIM + 16]);
        }
        o0 = __builtin_amdgcn_mfma_f32_16x16x32_bf16(pa, vb0, o0, 0, 0, 0);
        o1 = __builtin_amdgcn_mfma_f32_16x16x32_bf16(pa, vb1, o1, 0, 0, 0);
    }
    __syncthreads();     // all p_lds reads done; obuf may alias now

    // ---- cross-wave O reduce: obuf[w][q][d]
#pragma unroll
    for (int j = 0; j < 4; j++) {
        obuf[w * 512 + (lg * 4 + j) * 32 + lq]      = o0[j];
        obuf[w * 512 + (lg * 4 + j) * 32 + 16 + lq] = o1[j];
    }
    __syncthreads();
#pragma unroll
    for (int rep = 0; rep < 2; rep++) {
        int e = t + rep * 256;          // 0..511
        int q = e >> 5, d = e & 31;
        float s = obuf[e] + obuf[512 + e] + obuf[1024 + e] + obuf[1536 + e];
        O[((size_t)(c * SQL + qbase + q)) * DIM + h * HDIM + d] = s;
    }
}

// ---------------------------------------------------------------- driver

extern "C" void kernel_launch(void* const* d_in, const int* in_sizes, int n_in,
                              void* d_out, int out_size, void* d_ws, size_t ws_size,
                              hipStream_t stream) {
    const float* pose = (const float*)d_in[0];
    const float* vel  = (const float*)d_in[1];
    const float* img  = (const float*)d_in[2];
    const float* Wq   = (const float*)d_in[3];
    const float* bq   = (const float*)d_in[4];
    const float* Wk   = (const float*)d_in[5];
    const float* bk   = (const float*)d_in[6];
    const float* Wv   = (const float*)d_in[7];
    const float* bv   = (const float*)d_in[8];
    const float* Wo   = (const float*)d_in[9];
    const float* bo   = (const float*)d_in[10];
    const float* an_g = (const float*)d_in[11];
    const float* an_b = (const float*)d_in[12];
    const float* W1   = (const float*)d_in[13];
    const float* b1   = (const float*)d_in[14];
    const float* W2   = (const float*)d_in[15];
    const float* b2   = (const float*)d_in[16];
    const float* fn_g = (const float*)d_in[17];
    const float* fn_b = (const float*)d_in[18];
    const float* n_g  = (const float*)d_in[19];
    const float* n_b  = (const float*)d_in[20];

    float* ws = (float*)d_ws;
    const size_t SZ = (size_t)ROWS * DIM;       // 1M floats
    float* X    = ws;
    float* KVIN = X + SZ;
    float* T1   = KVIN + SZ;
    float* T2   = T1 + SZ;
    float* X1b  = T2 + SZ;
    float* Qb   = X1b + SZ;
    float* Kb   = Qb + SZ;
    float* Vb   = Kb + SZ;
    float* FFb  = Qb;                           // aliases Q/K/V (free by then)

    {
        int total = CB * SQL * DIM;
        init_kernel<<<(total + 255) / 256, 256, 0, stream>>>(pose, vel, img, X, KVIN);
    }

    dim3 g_d(DIM / 64, ROWS / 64);
    dim3 g_ff(FFD / 64, ROWS / 64);
    dim3 g_attn(SQL / 16, NH, CB);

    for (int i = 0; i < NL; i++) {
        const float* Wq_i = Wq + (size_t)i * DIM * DIM;
        const float* Wk_i = Wk + (size_t)i * DIM * DIM;
        const float* Wv_i = Wv + (size_t)i * DIM * DIM;
        const float* Wo_i = Wo + (size_t)i * DIM * DIM;
        const float* W1_i = W1 + (size_t)i * DIM * FFD;
        const float* W2_i = W2 + (size_t)i * FFD * DIM;

        gemm_bias<<<g_d, 256, 0, stream>>>(X,    Wq_i, bq + i * DIM, nullptr, Qb, ROWS, DIM, DIM, 0);
        gemm_bias<<<g_d, 256, 0, stream>>>(KVIN, Wk_i, bk + i * DIM, nullptr, Kb, ROWS, DIM, DIM, 0);
        gemm_bias<<<g_d, 256, 0, stream>>>(KVIN, Wv_i, bv + i * DIM, nullptr, Vb, ROWS, DIM, DIM, 0);

        attn_mfma<<<g_attn, 256, 0, stream>>>(Qb, Kb, Vb, T1);

        gemm_bias<<<g_d, 256, 0, stream>>>(T1, Wo_i, bo + i * DIM, nullptr, T2, ROWS, DIM, DIM, 0);

        ln_kernel<<<ROWS, 256, 0, stream>>>(T2, X, an_g + i * DIM, an_b + i * DIM, X1b);
        ln_kernel<<<ROWS, 256, 0, stream>>>(X1b, nullptr, fn_g + i * DIM, fn_b + i * DIM, T1);

        gemm_bias<<<g_ff, 256, 0, stream>>>(T1, W1_i, b1 + i * FFD, nullptr, FFb, ROWS, FFD, DIM, 1);
        gemm_bias<<<g_d, 256, 0, stream>>>(FFb, W2_i, b2 + i * DIM, X1b, T2, ROWS, DIM, FFD, 0);

        float* outp = (i == NL - 1) ? (float*)d_out : X;
        ln_kernel<<<ROWS, 256, 0, stream>>>(T2, X, n_g + i * DIM, n_b + i * DIM, outp);
    }

    (void)in_sizes; (void)n_in; (void)out_size; (void)ws_size;
}

// Round 4
// 745.470 us; speedup vs baseline: 11.7300x; 1.5358x over previous
//
#include <hip/hip_runtime.h>
#include <math.h>

#define NL   4
#define DIM  256
#define NH   8
#define HDIM 32
#define SQL  1024
#define SKL  1024
#define FFD  768
#define CB   4              // combined batch: 2 stacks * 2 batch
#define ROWS (CB * SQL)     // 4096

typedef __attribute__((ext_vector_type(8))) short bf16x8;
typedef __attribute__((ext_vector_type(4))) short bf16x4;
typedef __attribute__((ext_vector_type(4))) float f32x4;

// ---------------------------------------------------------------- utilities

__device__ __forceinline__ float mishf(float x) {
    float sp = (x > 20.0f) ? x : log1pf(expf(x));
    return x * tanhf(sp);
}

__device__ __forceinline__ short f2bf(float f) {
    union { float f; unsigned u; } v; v.f = f;
    unsigned u = v.u + 0x7fffu + ((v.u >> 16) & 1u);   // RNE
    return (short)(u >> 16);
}

// ---------------------------------------------------------------- init
// X fp32 + Xb bf16 (pose broadcast), KVb bf16 (vel, img)

__global__ __launch_bounds__(256) void init_kernel(
        const float* __restrict__ pose, const float* __restrict__ vel,
        const float* __restrict__ img, float* __restrict__ X,
        short* __restrict__ Xb, short* __restrict__ KVb) {
    int idx = blockIdx.x * 256 + threadIdx.x;
    if (idx >= CB * SQL * DIM) return;
    int c = idx / (SQL * DIM);
    int rem = idx - c * (SQL * DIM);
    int b = c & 1;
    float pv = pose[b * SQL * DIM + rem];
    X[idx]  = pv;
    Xb[idx] = f2bf(pv);
    const float* kv = (c < 2) ? vel : img;
    KVb[idx] = f2bf(kv[b * SQL * DIM + rem]);
}

// ---------------------------------------------------------------- weight transpose
// dst[l][n][k] = bf16(src[l][k][n]);  grid (N/64, K/64, L), 256 thr

__global__ __launch_bounds__(256) void transpose_w(
        const float* __restrict__ src, short* __restrict__ dst, int K, int N) {
    __shared__ float tile[64][65];
    int t = threadIdx.x;
    int n0 = blockIdx.x * 64, k0 = blockIdx.y * 64;
    const float* s = src + (size_t)blockIdx.z * K * N;
    short* d = dst + (size_t)blockIdx.z * K * N;
#pragma unroll
    for (int i = 0; i < 16; i++) {
        int idx = t + i * 256;
        int r = idx >> 6, c = idx & 63;          // r: k, c: n
        tile[r][c] = s[(size_t)(k0 + r) * N + n0 + c];
    }
    __syncthreads();
#pragma unroll
    for (int i = 0; i < 16; i++) {
        int idx = t + i * 256;
        int r = idx >> 6, c = idx & 63;          // r: n, c: k
        d[(size_t)(n0 + r) * K + k0 + c] = f2bf(tile[c][r]);
    }
}

// ---------------------------------------------------------------- bf16 MFMA GEMM
// C[M,N] = act(A[M,K] @ W[K,N] + bias) (+res). A bf16 [M][K], Wt bf16 [N][K].
// Block 256 thr = 4 waves, tile 64(M)x64(N), wave owns 16 rows. No LDS.
// Outputs: outf fp32, outb bf16 (x scale), outbT bf16 transposed [CB][DIM][SKL].

__global__ __launch_bounds__(256) void gemm_mfma(
        const short* __restrict__ A, const short* __restrict__ Wt,
        const float* __restrict__ bias, const float* __restrict__ res,
        float* __restrict__ outf, short* __restrict__ outb,
        short* __restrict__ outbT,
        int M, int N, int K, int act, float scale) {
    int t = threadIdx.x, l = t & 63, w = t >> 6;
    int lq = l & 15, lg = l >> 4;
    int bm = blockIdx.y * 64, bn = blockIdx.x * 64;

    const short* ap = A + (size_t)(bm + w * 16 + lq) * K + lg * 8;
    const short* wp = Wt + (size_t)(bn + lq) * K + lg * 8;

    f32x4 acc[4];
#pragma unroll
    for (int nt = 0; nt < 4; nt++) acc[nt] = (f32x4){0.f, 0.f, 0.f, 0.f};

#pragma unroll 8
    for (int k0 = 0; k0 < K; k0 += 32) {
        bf16x8 af = *(const bf16x8*)(ap + k0);
#pragma unroll
        for (int nt = 0; nt < 4; nt++) {
            bf16x8 bf = *(const bf16x8*)(wp + (size_t)nt * 16 * K + k0);
            acc[nt] = __builtin_amdgcn_mfma_f32_16x16x32_bf16(af, bf, acc[nt], 0, 0, 0);
        }
    }

    int ms = bm + w * 16 + lg * 4;               // first of 4 consecutive rows
#pragma unroll
    for (int nt = 0; nt < 4; nt++) {
        int col = bn + nt * 16 + lq;
        float bv = bias[col];
        float v[4];
#pragma unroll
        for (int j = 0; j < 4; j++) {
            float x = acc[nt][j] + bv;
            if (act == 1) x = mishf(x);
            if (res) x += res[(size_t)(ms + j) * N + col];
            v[j] = x;
        }
        if (outf) {
#pragma unroll
            for (int j = 0; j < 4; j++) outf[(size_t)(ms + j) * N + col] = v[j];
        }
        if (outb) {
#pragma unroll
            for (int j = 0; j < 4; j++) outb[(size_t)(ms + j) * N + col] = f2bf(v[j] * scale);
        }
        if (outbT) {                             // V: [c][d=col][k], rows are k
            int cc = ms >> 10, kl = ms & 1023;
            bf16x4 pk;
#pragma unroll
            for (int j = 0; j < 4; j++) pk[j] = f2bf(v[j]);
            *(bf16x4*)(outbT + ((size_t)(cc * DIM + col)) * SKL + kl) = pk;
        }
    }
}

// ---------------------------------------------------------------- fused LN pair
// x1 = res + LN(in)*ag+ab ;  y = LN(x1)*fg+fb
// out: x1 (fp32), y (bf16). One block per row.

__global__ __launch_bounds__(256) void ln2_kernel(
        const float* __restrict__ in, const float* __restrict__ res,
        const float* __restrict__ ag, const float* __restrict__ ab,
        const float* __restrict__ fg, const float* __restrict__ fb,
        float* __restrict__ x1out, short* __restrict__ yout) {
    int row = blockIdx.x, t = threadIdx.x;
    __shared__ float ws[4], ws2[4];
    __shared__ float mean_s, rstd_s;
    int wid = t >> 6, lane = t & 63;

    float v = in[(size_t)row * DIM + t];
    float s = v, s2 = v * v;
#pragma unroll
    for (int off = 32; off; off >>= 1) { s += __shfl_down(s, off); s2 += __shfl_down(s2, off); }
    if (lane == 0) { ws[wid] = s; ws2[wid] = s2; }
    __syncthreads();
    if (t == 0) {
        float S = ws[0] + ws[1] + ws[2] + ws[3];
        float S2 = ws2[0] + ws2[1] + ws2[2] + ws2[3];
        float m = S * (1.0f / DIM);
        float va = S2 * (1.0f / DIM) - m * m;
        mean_s = m; rstd_s = rsqrtf(va + 1e-5f);
    }
    __syncthreads();
    float x1 = res[(size_t)row * DIM + t] + (v - mean_s) * rstd_s * ag[t] + ab[t];

    s = x1; s2 = x1 * x1;
#pragma unroll
    for (int off = 32; off; off >>= 1) { s += __shfl_down(s, off); s2 += __shfl_down(s2, off); }
    if (lane == 0) { ws[wid] = s; ws2[wid] = s2; }
    __syncthreads();
    if (t == 0) {
        float S = ws[0] + ws[1] + ws[2] + ws[3];
        float S2 = ws2[0] + ws2[1] + ws2[2] + ws2[3];
        float m = S * (1.0f / DIM);
        float va = S2 * (1.0f / DIM) - m * m;
        mean_s = m; rstd_s = rsqrtf(va + 1e-5f);
    }
    __syncthreads();
    x1out[(size_t)row * DIM + t] = x1;
    yout[(size_t)row * DIM + t]  = f2bf((x1 - mean_s) * rstd_s * fg[t] + fb[t]);
}

// ---------------------------------------------------------------- final LN
// o = res + LN(in)*g+b -> outf fp32 (+ outb bf16 if non-null)

__global__ __launch_bounds__(256) void ln_final(
        const float* __restrict__ in, const float* __restrict__ res,
        const float* __restrict__ g, const float* __restrict__ b,
        float* __restrict__ outf, short* __restrict__ outb) {
    int row = blockIdx.x, t = threadIdx.x;
    __shared__ float ws[4], ws2[4];
    __shared__ float mean_s, rstd_s;
    int wid = t >> 6, lane = t & 63;

    float v = in[(size_t)row * DIM + t];
    float s = v, s2 = v * v;
#pragma unroll
    for (int off = 32; off; off >>= 1) { s += __shfl_down(s, off); s2 += __shfl_down(s2, off); }
    if (lane == 0) { ws[wid] = s; ws2[wid] = s2; }
    __syncthreads();
    if (t == 0) {
        float S = ws[0] + ws[1] + ws[2] + ws[3];
        float S2 = ws2[0] + ws2[1] + ws2[2] + ws2[3];
        float m = S * (1.0f / DIM);
        float va = S2 * (1.0f / DIM) - m * m;
        mean_s = m; rstd_s = rsqrtf(va + 1e-5f);
    }
    __syncthreads();
    float o = res[(size_t)row * DIM + t] + (v - mean_s) * rstd_s * g[t] + b[t];
    outf[(size_t)row * DIM + t] = o;
    if (outb) outb[(size_t)row * DIM + t] = f2bf(o);
}

// ---------------------------------------------------------------- attention (all-bf16)
// Q bf16 pre-scaled [c][q][D], K bf16 [c][k][D], Vt bf16 [c][d][k]. Out bf16.
// grid: (SQL/16, NH, CB), 256 threads.

__global__ __launch_bounds__(256) void attn_mfma(
        const short* __restrict__ Q, const short* __restrict__ K,
        const short* __restrict__ Vt, short* __restrict__ O) {
    int h = blockIdx.y, c = blockIdx.z;
    int qbase = blockIdx.x * 16;
    int t = threadIdx.x, l = t & 63, w = t >> 6;
    int lq = l & 15, lg = l >> 4;

    __shared__ __align__(16) short p_lds[16 * 1024];   // [q][k] bf16, XOR-swizzled
    __shared__ float redf[3][4][16];
    float* obuf = (float*)p_lds;                       // aliased after barrier

    bf16x8 qfrag = *(const bf16x8*)(Q + ((size_t)(c * SQL + qbase + lq)) * DIM + h * HDIM + lg * 8);

    // ---- QK^T: acc[kt][j] = S[k = 256w+16kt+4lg+j][q=lq]
    const int kw = w * 256;
    f32x4 acc[16];
#pragma unroll
    for (int kt = 0; kt < 16; kt++) {
        bf16x8 kf = *(const bf16x8*)(K + ((size_t)(c * SKL + kw + kt * 16 + lq)) * DIM + h * HDIM + lg * 8);
        f32x4 z = {0.f, 0.f, 0.f, 0.f};
        acc[kt] = __builtin_amdgcn_mfma_f32_16x16x32_bf16(kf, qfrag, z, 0, 0, 0);
    }

    // ---- row max, shift
    float m = acc[0][0];
#pragma unroll
    for (int kt = 0; kt < 16; kt++)
#pragma unroll
        for (int j = 0; j < 4; j++) m = fmaxf(m, acc[kt][j]);
    m = fmaxf(m, __shfl_xor(m, 16));
    m = fmaxf(m, __shfl_xor(m, 32));
    if (l < 16) redf[0][w][l] = m;
    __syncthreads();
    m = fmaxf(fmaxf(redf[0][0][lq], redf[0][1][lq]),
              fmaxf(redf[0][2][lq], redf[0][3][lq]));
#pragma unroll
    for (int kt = 0; kt < 16; kt++)
#pragma unroll
        for (int j = 0; j < 4; j++) acc[kt][j] -= m;

    // ---- bisection: f(tau) = sum clip(x-tau)^2 = 1, tau* in [-1, -1/32]
    float lo = -1.0f, hi = -0.03125f;
#pragma unroll 1
    for (int it = 0; it < 12; it++) {
        float tau = 0.5f * (lo + hi);
        float f = 0.f;
#pragma unroll
        for (int kt = 0; kt < 16; kt++)
#pragma unroll
            for (int j = 0; j < 4; j++) {
                float d = fmaxf(acc[kt][j] - tau, 0.f);
                f += d * d;
            }
        f += __shfl_xor(f, 16);
        f += __shfl_xor(f, 32);
        __syncthreads();
        if (l < 16) redf[0][w][l] = f;
        __syncthreads();
        f = redf[0][0][lq] + redf[0][1][lq] + redf[0][2][lq] + redf[0][3][lq];
        if (f >= 1.0f) lo = tau; else hi = tau;
    }
    float tau = 0.5f * (lo + hi);

    // ---- 2 closed-form support refinements
#pragma unroll 1
    for (int r = 0; r < 2; r++) {
        float n = 0.f, s1 = 0.f, s2 = 0.f;
#pragma unroll
        for (int kt = 0; kt < 16; kt++)
#pragma unroll
            for (int j = 0; j < 4; j++) {
                float xv = acc[kt][j];
                if (xv > tau) { n += 1.f; s1 += xv; s2 += xv * xv; }
            }
        n  += __shfl_xor(n, 16);  n  += __shfl_xor(n, 32);
        s1 += __shfl_xor(s1, 16); s1 += __shfl_xor(s1, 32);
        s2 += __shfl_xor(s2, 16); s2 += __shfl_xor(s2, 32);
        __syncthreads();
        if (l < 16) { redf[0][w][l] = n; redf[1][w][l] = s1; redf[2][w][l] = s2; }
        __syncthreads();
        n  = redf[0][0][lq] + redf[0][1][lq] + redf[0][2][lq] + redf[0][3][lq];
        s1 = redf[1][0][lq] + redf[1][1][lq] + redf[1][2][lq] + redf[1][3][lq];
        s2 = redf[2][0][lq] + redf[2][1][lq] + redf[2][2][lq] + redf[2][3][lq];
        float disc = fmaxf(s1 * s1 - n * (s2 - 1.0f), 0.f);
        tau = fminf(fmaxf((s1 - sqrtf(disc)) / n, -1.0f), -0.03125f);
    }

    // ---- p = clip(x-tau)^2 -> bf16 -> swizzled LDS [q=lq][k], byte ^= lq<<4
#pragma unroll
    for (int kt = 0; kt < 16; kt++) {
        float d0 = fmaxf(acc[kt][0] - tau, 0.f);
        float d1 = fmaxf(acc[kt][1] - tau, 0.f);
        float d2 = fmaxf(acc[kt][2] - tau, 0.f);
        float d3 = fmaxf(acc[kt][3] - tau, 0.f);
        unsigned p01 = (unsigned short)f2bf(d0 * d0) | ((unsigned)(unsigned short)f2bf(d1 * d1) << 16);
        unsigned p23 = (unsigned short)f2bf(d2 * d2) | ((unsigned)(unsigned short)f2bf(d3 * d3) << 16);
        int k = kw + kt * 16 + lg * 4;
        int byte = lq * 2048 + ((k * 2) ^ (lq << 4));
        *(uint2*)((char*)p_lds + byte) = make_uint2(p01, p23);
    }
    __syncthreads();

    // ---- PV: wave sums its k-quarter; V frags contiguous from Vt
    f32x4 o0 = {0.f, 0.f, 0.f, 0.f}, o1 = {0.f, 0.f, 0.f, 0.f};
#pragma unroll
    for (int kt2 = 0; kt2 < 8; kt2++) {
        int k0 = kw + kt2 * 32 + lg * 8;
        int byte = lq * 2048 + ((k0 * 2) ^ (lq << 4));
        bf16x8 pa = *(const bf16x8*)((const char*)p_lds + byte);
        bf16x8 vb0 = *(const bf16x8*)(Vt + ((size_t)(c * DIM + h * HDIM + lq)) * SKL + k0);
        bf16x8 vb1 = *(const bf16x8*)(Vt + ((size_t)(c * DIM + h * HDIM + 16 + lq)) * SKL + k0);
        o0 = __builtin_amdgcn_mfma_f32_16x16x32_bf16(pa, vb0, o0, 0, 0, 0);
        o1 = __builtin_amdgcn_mfma_f32_16x16x32_bf16(pa, vb1, o1, 0, 0, 0);
    }
    __syncthreads();

    // ---- cross-wave O reduce: obuf[w][q][d]
#pragma unroll
    for (int j = 0; j < 4; j++) {
        obuf[w * 512 + (lg * 4 + j) * 32 + lq]      = o0[j];
        obuf[w * 512 + (lg * 4 + j) * 32 + 16 + lq] = o1[j];
    }
    __syncthreads();
#pragma unroll
    for (int rep = 0; rep < 2; rep++) {
        int e = t + rep * 256;
        int q = e >> 5, d = e & 31;
        float s = obuf[e] + obuf[512 + e] + obuf[1024 + e] + obuf[1536 + e];
        O[((size_t)(c * SQL + qbase + q)) * DIM + h * HDIM + d] = f2bf(s);
    }
}

// ---------------------------------------------------------------- driver

extern "C" void kernel_launch(void* const* d_in, const int* in_sizes, int n_in,
                              void* d_out, int out_size, void* d_ws, size_t ws_size,
                              hipStream_t stream) {
    const float* pose = (const float*)d_in[0];
    const float* vel  = (const float*)d_in[1];
    const float* img  = (const float*)d_in[2];
    const float* Wq   = (const float*)d_in[3];
    const float* bq   = (const float*)d_in[4];
    const float* Wk   = (const float*)d_in[5];
    const float* bk   = (const float*)d_in[6];
    const float* Wv   = (const float*)d_in[7];
    const float* bv   = (const float*)d_in[8];
    const float* Wo   = (const float*)d_in[9];
    const float* bo   = (const float*)d_in[10];
    const float* an_g = (const float*)d_in[11];
    const float* an_b = (const float*)d_in[12];
    const float* W1   = (const float*)d_in[13];
    const float* b1   = (const float*)d_in[14];
    const float* W2   = (const float*)d_in[15];
    const float* b2   = (const float*)d_in[16];
    const float* fn_g = (const float*)d_in[17];
    const float* fn_b = (const float*)d_in[18];
    const float* n_g  = (const float*)d_in[19];
    const float* n_b  = (const float*)d_in[20];

    const size_t SZ = (size_t)ROWS * DIM;           // 1M elements
    float* X    = (float*)d_ws;
    float* T2   = X + SZ;
    float* X1b  = T2 + SZ;
    short* Xb   = (short*)(X1b + SZ);
    short* KVb  = Xb + SZ;
    short* T1b  = KVb + SZ;
    short* Qb   = T1b + SZ;
    short* Kb   = Qb + SZ;
    short* Vt   = Kb + SZ;                          // [CB][DIM][SKL]
    short* FFb  = Qb;                               // [4096][768] aliases Qb..Vt
    short* Wqt  = Vt + SZ;
    short* Wkt  = Wqt + (size_t)NL * DIM * DIM;
    short* Wvt  = Wkt + (size_t)NL * DIM * DIM;
    short* Wot  = Wvt + (size_t)NL * DIM * DIM;
    short* W1t  = Wot + (size_t)NL * DIM * DIM;     // [L][768][256]
    short* W2t  = W1t + (size_t)NL * DIM * FFD;     // [L][256][768]

    {
        int total = CB * SQL * DIM;
        init_kernel<<<(total + 255) / 256, 256, 0, stream>>>(pose, vel, img, X, Xb, KVb);
    }
    transpose_w<<<dim3(DIM / 64, DIM / 64, NL), 256, 0, stream>>>(Wq, Wqt, DIM, DIM);
    transpose_w<<<dim3(DIM / 64, DIM / 64, NL), 256, 0, stream>>>(Wk, Wkt, DIM, DIM);
    transpose_w<<<dim3(DIM / 64, DIM / 64, NL), 256, 0, stream>>>(Wv, Wvt, DIM, DIM);
    transpose_w<<<dim3(DIM / 64, DIM / 64, NL), 256, 0, stream>>>(Wo, Wot, DIM, DIM);
    transpose_w<<<dim3(FFD / 64, DIM / 64, NL), 256, 0, stream>>>(W1, W1t, DIM, FFD);
    transpose_w<<<dim3(DIM / 64, FFD / 64, NL), 256, 0, stream>>>(W2, W2t, FFD, DIM);

    const float qscale = 0.08838834764831845f;      // 0.5 / sqrt(32)
    dim3 g_d(DIM / 64, ROWS / 64);
    dim3 g_ff(FFD / 64, ROWS / 64);
    dim3 g_attn(SQL / 16, NH, CB);

    for (int i = 0; i < NL; i++) {
        const short* Wqt_i = Wqt + (size_t)i * DIM * DIM;
        const short* Wkt_i = Wkt + (size_t)i * DIM * DIM;
        const short* Wvt_i = Wvt + (size_t)i * DIM * DIM;
        const short* Wot_i = Wot + (size_t)i * DIM * DIM;
        const short* W1t_i = W1t + (size_t)i * DIM * FFD;
        const short* W2t_i = W2t + (size_t)i * DIM * FFD;

        gemm_mfma<<<g_d, 256, 0, stream>>>(Xb,  Wqt_i, bq + i * DIM, nullptr,
                                           nullptr, Qb, nullptr, ROWS, DIM, DIM, 0, qscale);
        gemm_mfma<<<g_d, 256, 0, stream>>>(KVb, Wkt_i, bk + i * DIM, nullptr,
                                           nullptr, Kb, nullptr, ROWS, DIM, DIM, 0, 1.0f);
        gemm_mfma<<<g_d, 256, 0, stream>>>(KVb, Wvt_i, bv + i * DIM, nullptr,
                                           nullptr, nullptr, Vt, ROWS, DIM, DIM, 0, 1.0f);

        attn_mfma<<<g_attn, 256, 0, stream>>>(Qb, Kb, Vt, T1b);

        gemm_mfma<<<g_d, 256, 0, stream>>>(T1b, Wot_i, bo + i * DIM, nullptr,
                                           T2, nullptr, nullptr, ROWS, DIM, DIM, 0, 1.0f);

        ln2_kernel<<<ROWS, 256, 0, stream>>>(T2, X, an_g + i * DIM, an_b + i * DIM,
                                             fn_g + i * DIM, fn_b + i * DIM, X1b, T1b);

        gemm_mfma<<<g_ff, 256, 0, stream>>>(T1b, W1t_i, b1 + i * FFD, nullptr,
                                            nullptr, FFb, nullptr, ROWS, FFD, DIM, 1, 1.0f);
        gemm_mfma<<<g_d, 256, 0, stream>>>(FFb, W2t_i, b2 + i * DIM, X1b,
                                           T2, nullptr, nullptr, ROWS, DIM, FFD, 0, 1.0f);

        float* outp = (i == NL - 1) ? (float*)d_out : X;
        short* outbp = (i == NL - 1) ? nullptr : Xb;
        ln_final<<<ROWS, 256, 0, stream>>>(T2, X, n_g + i * DIM, n_b + i * DIM, outp, outbp);
    }

    (void)in_sizes; (void)n_in; (void)out_size; (void)ws_size;
}

// Round 5
// 564.444 us; speedup vs baseline: 15.4919x; 1.3207x over previous
//
#include <hip/hip_runtime.h>
#include <math.h>

#define NL   4
#define DIM  256
#define NH   8
#define HDIM 32
#define SQL  1024
#define SKL  1024
#define FFD  768
#define CB   4              // combined batch: 2 stacks * 2 batch
#define ROWS (CB * SQL)     // 4096

typedef __attribute__((ext_vector_type(8))) short bf16x8;
typedef __attribute__((ext_vector_type(4))) short bf16x4;
typedef __attribute__((ext_vector_type(4))) float f32x4;

// ---------------------------------------------------------------- utilities

__device__ __forceinline__ float mishf(float x) {
    float sp = (x > 20.0f) ? x : log1pf(expf(x));
    return x * tanhf(sp);
}

__device__ __forceinline__ short f2bf(float f) {
    union { float f; unsigned u; } v; v.f = f;
    unsigned u = v.u + 0x7fffu + ((v.u >> 16) & 1u);   // RNE
    return (short)(u >> 16);
}

// ---------------------------------------------------------------- init

__global__ __launch_bounds__(256) void init_kernel(
        const float* __restrict__ pose, const float* __restrict__ vel,
        const float* __restrict__ img, float* __restrict__ X,
        short* __restrict__ Xb, short* __restrict__ KVb) {
    int idx = blockIdx.x * 256 + threadIdx.x;
    if (idx >= CB * SQL * DIM) return;
    int c = idx / (SQL * DIM);
    int rem = idx - c * (SQL * DIM);
    int b = c & 1;
    float pv = pose[b * SQL * DIM + rem];
    X[idx]  = pv;
    Xb[idx] = f2bf(pv);
    const float* kv = (c < 2) ? vel : img;
    KVb[idx] = f2bf(kv[b * SQL * DIM + rem]);
}

// ---------------------------------------------------------------- weight transposes
// batched Wq/Wk/Wv/Wo: z = mat*4 + layer; dst[n][k] = bf16(src[k][n])

__global__ __launch_bounds__(256) void transpose_qkvo(
        const float* __restrict__ Wq, const float* __restrict__ Wk,
        const float* __restrict__ Wv, const float* __restrict__ Wo,
        short* __restrict__ Wqt, short* __restrict__ Wkt,
        short* __restrict__ Wvt, short* __restrict__ Wot) {
    __shared__ float tile[64][65];
    int z = blockIdx.z, m = z >> 2, lyr = z & 3;
    const float* src = ((m == 0) ? Wq : (m == 1) ? Wk : (m == 2) ? Wv : Wo)
                       + (size_t)lyr * DIM * DIM;
    short* dst = ((m == 0) ? Wqt : (m == 1) ? Wkt : (m == 2) ? Wvt : Wot)
                 + (size_t)lyr * DIM * DIM;
    int t = threadIdx.x;
    int n0 = blockIdx.x * 64, k0 = blockIdx.y * 64;
#pragma unroll
    for (int i = 0; i < 16; i++) {
        int idx = t + i * 256;
        int r = idx >> 6, c = idx & 63;
        tile[r][c] = src[(size_t)(k0 + r) * DIM + n0 + c];
    }
    __syncthreads();
#pragma unroll
    for (int i = 0; i < 16; i++) {
        int idx = t + i * 256;
        int r = idx >> 6, c = idx & 63;
        dst[(size_t)(n0 + r) * DIM + k0 + c] = f2bf(tile[c][r]);
    }
}

__global__ __launch_bounds__(256) void transpose_w(
        const float* __restrict__ src, short* __restrict__ dst, int K, int N) {
    __shared__ float tile[64][65];
    int t = threadIdx.x;
    int n0 = blockIdx.x * 64, k0 = blockIdx.y * 64;
    const float* s = src + (size_t)blockIdx.z * K * N;
    short* d = dst + (size_t)blockIdx.z * K * N;
#pragma unroll
    for (int i = 0; i < 16; i++) {
        int idx = t + i * 256;
        int r = idx >> 6, c = idx & 63;
        tile[r][c] = s[(size_t)(k0 + r) * N + n0 + c];
    }
    __syncthreads();
#pragma unroll
    for (int i = 0; i < 16; i++) {
        int idx = t + i * 256;
        int r = idx >> 6, c = idx & 63;
        d[(size_t)(n0 + r) * K + k0 + c] = f2bf(tile[c][r]);
    }
}

// ---------------------------------------------------------------- QKV batched GEMM
// grid (DIM/64, ROWS/64, 3): z=0 Q (scaled), z=1 K, z=2 V (transposed out)

__global__ __launch_bounds__(256) void qkv_gemm(
        const short* __restrict__ Xb, const short* __restrict__ KVb,
        const short* __restrict__ Wqt, const short* __restrict__ Wkt,
        const short* __restrict__ Wvt,
        const float* __restrict__ bq, const float* __restrict__ bk,
        const float* __restrict__ bv,
        short* __restrict__ Qb, short* __restrict__ Kb, short* __restrict__ Vt,
        float qscale) {
    int z = blockIdx.z;
    const short* A    = (z == 0) ? Xb : KVb;
    const short* Wt   = (z == 0) ? Wqt : (z == 1) ? Wkt : Wvt;
    const float* bias = (z == 0) ? bq : (z == 1) ? bk : bv;
    float scale = (z == 0) ? qscale : 1.0f;

    int t = threadIdx.x, l = t & 63, w = t >> 6;
    int lq = l & 15, lg = l >> 4;
    int bm = blockIdx.y * 64, bn = blockIdx.x * 64;

    const short* ap = A + (size_t)(bm + w * 16 + lq) * DIM + lg * 8;
    const short* wp = Wt + (size_t)(bn + lq) * DIM + lg * 8;

    f32x4 acc[4];
#pragma unroll
    for (int nt = 0; nt < 4; nt++) acc[nt] = (f32x4){0.f, 0.f, 0.f, 0.f};
#pragma unroll
    for (int k0 = 0; k0 < DIM; k0 += 32) {
        bf16x8 af = *(const bf16x8*)(ap + k0);
#pragma unroll
        for (int nt = 0; nt < 4; nt++) {
            bf16x8 bfr = *(const bf16x8*)(wp + (size_t)nt * 16 * DIM + k0);
            acc[nt] = __builtin_amdgcn_mfma_f32_16x16x32_bf16(af, bfr, acc[nt], 0, 0, 0);
        }
    }

    int ms = bm + w * 16 + lg * 4;
#pragma unroll
    for (int nt = 0; nt < 4; nt++) {
        int col = bn + nt * 16 + lq;
        float bv_ = bias[col];
        float v[4];
#pragma unroll
        for (int j = 0; j < 4; j++) v[j] = acc[nt][j] + bv_;
        if (z < 2) {
            short* out = (z == 0) ? Qb : Kb;
#pragma unroll
            for (int j = 0; j < 4; j++) out[(size_t)(ms + j) * DIM + col] = f2bf(v[j] * scale);
        } else {
            int cc = ms >> 10, kl = ms & 1023;
            bf16x4 pk;
#pragma unroll
            for (int j = 0; j < 4; j++) pk[j] = f2bf(v[j]);
            *(bf16x4*)(Vt + ((size_t)(cc * DIM + col)) * SKL + kl) = pk;
        }
    }
}

// ---------------------------------------------------------------- W1 GEMM (mish)
// out[M,768] = mish(A[M,256] @ W1 + b1), bf16 out. grid (FFD/64, ROWS/64).

__global__ __launch_bounds__(256) void gemm_mish(
        const short* __restrict__ A, const short* __restrict__ Wt,
        const float* __restrict__ bias, short* __restrict__ outb) {
    int t = threadIdx.x, l = t & 63, w = t >> 6;
    int lq = l & 15, lg = l >> 4;
    int bm = blockIdx.y * 64, bn = blockIdx.x * 64;

    const short* ap = A + (size_t)(bm + w * 16 + lq) * DIM + lg * 8;
    const short* wp = Wt + (size_t)(bn + lq) * DIM + lg * 8;

    f32x4 acc[4];
#pragma unroll
    for (int nt = 0; nt < 4; nt++) acc[nt] = (f32x4){0.f, 0.f, 0.f, 0.f};
#pragma unroll
    for (int k0 = 0; k0 < DIM; k0 += 32) {
        bf16x8 af = *(const bf16x8*)(ap + k0);
#pragma unroll
        for (int nt = 0; nt < 4; nt++) {
            bf16x8 bfr = *(const bf16x8*)(wp + (size_t)nt * 16 * DIM + k0);
            acc[nt] = __builtin_amdgcn_mfma_f32_16x16x32_bf16(af, bfr, acc[nt], 0, 0, 0);
        }
    }
    int ms = bm + w * 16 + lg * 4;
#pragma unroll
    for (int nt = 0; nt < 4; nt++) {
        int col = bn + nt * 16 + lq;
        float bv_ = bias[col];
#pragma unroll
        for (int j = 0; j < 4; j++)
            outb[(size_t)(ms + j) * FFD + col] = f2bf(mishf(acc[nt][j] + bv_));
    }
}

// ---------------------------------------------------------------- GEMM + double LN
// G = A@Wo + bo; x1 = X + LN(G)*ag+ab; y = LN(x1)*fg+fb.
// Block: 16 rows x 256 cols, 4 waves (wave w -> cols 64w..64w+63). grid (ROWS/16).

__global__ __launch_bounds__(256) void gemm_ln2(
        const short* __restrict__ A, const short* __restrict__ Wt,
        const float* __restrict__ bias, const float* __restrict__ Xres,
        const float* __restrict__ ag, const float* __restrict__ ab,
        const float* __restrict__ fg, const float* __restrict__ fb,
        float* __restrict__ x1out, short* __restrict__ yout) {
    __shared__ float gbuf[16][264];
    int t = threadIdx.x, l = t & 63, w = t >> 6;
    int lq = l & 15, lg = l >> 4;
    int bm = blockIdx.x * 16;

    const short* ap = A + (size_t)(bm + lq) * DIM + lg * 8;
    const short* wp = Wt + (size_t)(w * 64 + lq) * DIM + lg * 8;

    f32x4 acc[4];
#pragma unroll
    for (int nt = 0; nt < 4; nt++) acc[nt] = (f32x4){0.f, 0.f, 0.f, 0.f};
#pragma unroll
    for (int k0 = 0; k0 < DIM; k0 += 32) {
        bf16x8 af = *(const bf16x8*)(ap + k0);
#pragma unroll
        for (int nt = 0; nt < 4; nt++) {
            bf16x8 bfr = *(const bf16x8*)(wp + (size_t)nt * 16 * DIM + k0);
            acc[nt] = __builtin_amdgcn_mfma_f32_16x16x32_bf16(af, bfr, acc[nt], 0, 0, 0);
        }
    }
#pragma unroll
    for (int nt = 0; nt < 4; nt++) {
        int col = w * 64 + nt * 16 + lq;
        float bv_ = bias[col];
#pragma unroll
        for (int j = 0; j < 4; j++) gbuf[lg * 4 + j][col] = acc[nt][j] + bv_;
    }
    __syncthreads();

    int g = t >> 4, u = t & 15;
    int row = bm + g;
    float s = 0.f, s2 = 0.f;
#pragma unroll
    for (int i = 0; i < 16; i++) {
        float v = gbuf[g][u + 16 * i];
        s += v; s2 += v * v;
    }
#pragma unroll
    for (int off = 1; off < 16; off <<= 1) { s += __shfl_xor(s, off); s2 += __shfl_xor(s2, off); }
    float m = s * (1.f / DIM);
    float rstd = rsqrtf(s2 * (1.f / DIM) - m * m + 1e-5f);

    float x1v[16];
    float sb = 0.f, sb2 = 0.f;
#pragma unroll
    for (int i = 0; i < 16; i++) {
        int col = u + 16 * i;
        float x1 = Xres[(size_t)row * DIM + col] + (gbuf[g][col] - m) * rstd * ag[col] + ab[col];
        x1v[i] = x1; sb += x1; sb2 += x1 * x1;
    }
#pragma unroll
    for (int off = 1; off < 16; off <<= 1) { sb += __shfl_xor(sb, off); sb2 += __shfl_xor(sb2, off); }
    float m2 = sb * (1.f / DIM);
    float rstd2 = rsqrtf(sb2 * (1.f / DIM) - m2 * m2 + 1e-5f);
#pragma unroll
    for (int i = 0; i < 16; i++) {
        int col = u + 16 * i;
        x1out[(size_t)row * DIM + col] = x1v[i];
        yout[(size_t)row * DIM + col]  = f2bf((x1v[i] - m2) * rstd2 * fg[col] + fb[col]);
    }
}

// ---------------------------------------------------------------- GEMM + final LN
// x2 = FF@W2 + b2 + x1; out = X + LN(x2)*g+b -> outf fp32 (+ outb bf16). K=768.

__global__ __launch_bounds__(256) void gemm_lnf(
        const short* __restrict__ A, const short* __restrict__ Wt,
        const float* __restrict__ bias, const float* __restrict__ x1res,
        const float* __restrict__ Xres, const float* __restrict__ g_,
        const float* __restrict__ b_,
        float* __restrict__ outf, short* __restrict__ outb) {
    __shared__ float gbuf[16][264];
    int t = threadIdx.x, l = t & 63, w = t >> 6;
    int lq = l & 15, lg = l >> 4;
    int bm = blockIdx.x * 16;

    const short* ap = A + (size_t)(bm + lq) * FFD + lg * 8;
    const short* wp = Wt + (size_t)(w * 64 + lq) * FFD + lg * 8;

    f32x4 acc[4];
#pragma unroll
    for (int nt = 0; nt < 4; nt++) acc[nt] = (f32x4){0.f, 0.f, 0.f, 0.f};
#pragma unroll 8
    for (int k0 = 0; k0 < FFD; k0 += 32) {
        bf16x8 af = *(const bf16x8*)(ap + k0);
#pragma unroll
        for (int nt = 0; nt < 4; nt++) {
            bf16x8 bfr = *(const bf16x8*)(wp + (size_t)nt * 16 * FFD + k0);
            acc[nt] = __builtin_amdgcn_mfma_f32_16x16x32_bf16(af, bfr, acc[nt], 0, 0, 0);
        }
    }
#pragma unroll
    for (int nt = 0; nt < 4; nt++) {
        int col = w * 64 + nt * 16 + lq;
        float bv_ = bias[col];
#pragma unroll
        for (int j = 0; j < 4; j++) {
            int row = bm + lg * 4 + j;
            gbuf[lg * 4 + j][col] = acc[nt][j] + bv_ + x1res[(size_t)row * DIM + col];
        }
    }
    __syncthreads();

    int g = t >> 4, u = t & 15;
    int row = bm + g;
    float s = 0.f, s2 = 0.f;
#pragma unroll
    for (int i = 0; i < 16; i++) {
        float v = gbuf[g][u + 16 * i];
        s += v; s2 += v * v;
    }
#pragma unroll
    for (int off = 1; off < 16; off <<= 1) { s += __shfl_xor(s, off); s2 += __shfl_xor(s2, off); }
    float m = s * (1.f / DIM);
    float rstd = rsqrtf(s2 * (1.f / DIM) - m * m + 1e-5f);
#pragma unroll
    for (int i = 0; i < 16; i++) {
        int col = u + 16 * i;
        float o = Xres[(size_t)row * DIM + col] + (gbuf[g][col] - m) * rstd * g_[col] + b_[col];
        outf[(size_t)row * DIM + col] = o;
        if (outb) outb[(size_t)row * DIM + col] = f2bf(o);
    }
}

// ---------------------------------------------------------------- attention (MFMA + Michelot entmax)
// grid (SQL/16, NH, CB), 256 threads = 4 waves; wave w owns k in [256w, 256w+256).

__global__ __launch_bounds__(256) void attn_mfma(
        const short* __restrict__ Q, const short* __restrict__ K,
        const short* __restrict__ Vt, short* __restrict__ O) {
    int h = blockIdx.y, c = blockIdx.z;
    int qbase = blockIdx.x * 16;
    int t = threadIdx.x, l = t & 63, w = t >> 6;
    int lq = l & 15, lg = l >> 4;

    __shared__ __align__(16) short p_lds[16 * 1024];   // [q][k] bf16, XOR-swizzled
    __shared__ float redf[3][4][16];
    float* obuf = (float*)p_lds;                       // aliased after barrier

    bf16x8 qfrag = *(const bf16x8*)(Q + ((size_t)(c * SQL + qbase + lq)) * DIM + h * HDIM + lg * 8);

    // ---- QK^T: acc[kt][j] = S[k = 256w+16kt+4lg+j][q=lq]
    const int kw = w * 256;
    f32x4 acc[16];
#pragma unroll
    for (int kt = 0; kt < 16; kt++) {
        bf16x8 kf = *(const bf16x8*)(K + ((size_t)(c * SKL + kw + kt * 16 + lq)) * DIM + h * HDIM + lg * 8);
        f32x4 z = {0.f, 0.f, 0.f, 0.f};
        acc[kt] = __builtin_amdgcn_mfma_f32_16x16x32_bf16(kf, qfrag, z, 0, 0, 0);
    }

    // ---- row max, shift
    float m = acc[0][0];
#pragma unroll
    for (int kt = 0; kt < 16; kt++)
#pragma unroll
        for (int j = 0; j < 4; j++) m = fmaxf(m, acc[kt][j]);
    m = fmaxf(m, __shfl_xor(m, 16));
    m = fmaxf(m, __shfl_xor(m, 32));
    if (l < 16) redf[0][w][l] = m;
    __syncthreads();
    m = fmaxf(fmaxf(redf[0][0][lq], redf[0][1][lq]),
              fmaxf(redf[0][2][lq], redf[0][3][lq]));
#pragma unroll
    for (int kt = 0; kt < 16; kt++)
#pragma unroll
        for (int j = 0; j < 4; j++) acc[kt][j] -= m;

    // ---- Michelot support iteration: S = {x > tau}; solve
    // n*t^2 - 2*S1*t + (S2-1) = 0 -> tau = (S1 - sqrt(S1^2 - n(S2-1)))/n.
    // tau* in [-1, -1/32]; tau0 = -1 gives support superset -> converges fast.
    float tau = -1.0f;
#pragma unroll 1
    for (int r = 0; r < 5; r++) {
        float n = 0.f, s1 = 0.f, s2 = 0.f;
#pragma unroll
        for (int kt = 0; kt < 16; kt++)
#pragma unroll
            for (int j = 0; j < 4; j++) {
                float xv = acc[kt][j];
                if (xv > tau) { n += 1.f; s1 += xv; s2 += xv * xv; }
            }
        n  += __shfl_xor(n, 16);  n  += __shfl_xor(n, 32);
        s1 += __shfl_xor(s1, 16); s1 += __shfl_xor(s1, 32);
        s2 += __shfl_xor(s2, 16); s2 += __shfl_xor(s2, 32);
        __syncthreads();
        if (l < 16) { redf[0][w][l] = n; redf[1][w][l] = s1; redf[2][w][l] = s2; }
        __syncthreads();
        n  = redf[0][0][lq] + redf[0][1][lq] + redf[0][2][lq] + redf[0][3][lq];
        s1 = redf[1][0][lq] + redf[1][1][lq] + redf[1][2][lq] + redf[1][3][lq];
        s2 = redf[2][0][lq] + redf[2][1][lq] + redf[2][2][lq] + redf[2][3][lq];
        float disc = fmaxf(s1 * s1 - n * (s2 - 1.0f), 0.f);
        tau = fminf(fmaxf((s1 - sqrtf(disc)) / n, -1.0f), -0.03125f);
    }

    // ---- p = clip(x-tau)^2 -> bf16 -> swizzled LDS [q=lq][k], byte ^= lq<<4
#pragma unroll
    for (int kt = 0; kt < 16; kt++) {
        float d0 = fmaxf(acc[kt][0] - tau, 0.f);
        float d1 = fmaxf(acc[kt][1] - tau, 0.f);
        float d2 = fmaxf(acc[kt][2] - tau, 0.f);
        float d3 = fmaxf(acc[kt][3] - tau, 0.f);
        unsigned p01 = (unsigned short)f2bf(d0 * d0) | ((unsigned)(unsigned short)f2bf(d1 * d1) << 16);
        unsigned p23 = (unsigned short)f2bf(d2 * d2) | ((unsigned)(unsigned short)f2bf(d3 * d3) << 16);
        int k = kw + kt * 16 + lg * 4;
        int byte = lq * 2048 + ((k * 2) ^ (lq << 4));
        *(uint2*)((char*)p_lds + byte) = make_uint2(p01, p23);
    }
    __syncthreads();

    // ---- PV: wave sums its k-quarter; V frags contiguous from Vt [c][d][k]
    f32x4 o0 = {0.f, 0.f, 0.f, 0.f}, o1 = {0.f, 0.f, 0.f, 0.f};
#pragma unroll
    for (int kt2 = 0; kt2 < 8; kt2++) {
        int k0 = kw + kt2 * 32 + lg * 8;
        int byte = lq * 2048 + ((k0 * 2) ^ (lq << 4));
        bf16x8 pa = *(const bf16x8*)((const char*)p_lds + byte);
        bf16x8 vb0 = *(const bf16x8*)(Vt + ((size_t)(c * DIM + h * HDIM + lq)) * SKL + k0);
        bf16x8 vb1 = *(const bf16x8*)(Vt + ((size_t)(c * DIM + h * HDIM + 16 + lq)) * SKL + k0);
        o0 = __builtin_amdgcn_mfma_f32_16x16x32_bf16(pa, vb0, o0, 0, 0, 0);
        o1 = __builtin_amdgcn_mfma_f32_16x16x32_bf16(pa, vb1, o1, 0, 0, 0);
    }
    __syncthreads();

    // ---- cross-wave O reduce
#pragma unroll
    for (int j = 0; j < 4; j++) {
        obuf[w * 512 + (lg * 4 + j) * 32 + lq]      = o0[j];
        obuf[w * 512 + (lg * 4 + j) * 32 + 16 + lq] = o1[j];
    }
    __syncthreads();
#pragma unroll
    for (int rep = 0; rep < 2; rep++) {
        int e = t + rep * 256;
        int q = e >> 5, d = e & 31;
        float s = obuf[e] + obuf[512 + e] + obuf[1024 + e] + obuf[1536 + e];
        O[((size_t)(c * SQL + qbase + q)) * DIM + h * HDIM + d] = f2bf(s);
    }
}

// ---------------------------------------------------------------- driver

extern "C" void kernel_launch(void* const* d_in, const int* in_sizes, int n_in,
                              void* d_out, int out_size, void* d_ws, size_t ws_size,
                              hipStream_t stream) {
    const float* pose = (const float*)d_in[0];
    const float* vel  = (const float*)d_in[1];
    const float* img  = (const float*)d_in[2];
    const float* Wq   = (const float*)d_in[3];
    const float* bq   = (const float*)d_in[4];
    const float* Wk   = (const float*)d_in[5];
    const float* bk   = (const float*)d_in[6];
    const float* Wv   = (const float*)d_in[7];
    const float* bv   = (const float*)d_in[8];
    const float* Wo   = (const float*)d_in[9];
    const float* bo   = (const float*)d_in[10];
    const float* an_g = (const float*)d_in[11];
    const float* an_b = (const float*)d_in[12];
    const float* W1   = (const float*)d_in[13];
    const float* b1   = (const float*)d_in[14];
    const float* W2   = (const float*)d_in[15];
    const float* b2   = (const float*)d_in[16];
    const float* fn_g = (const float*)d_in[17];
    const float* fn_b = (const float*)d_in[18];
    const float* n_g  = (const float*)d_in[19];
    const float* n_b  = (const float*)d_in[20];

    const size_t SZ = (size_t)ROWS * DIM;           // 1M elements
    float* X    = (float*)d_ws;                     // fp32 residual stream
    float* X1b  = X + SZ;                           // fp32 x1
    short* Xb   = (short*)(X1b + SZ);
    short* KVb  = Xb + SZ;
    short* T1b  = KVb + SZ;                         // attn out bf16
    short* Qb   = T1b + SZ;
    short* Kb   = Qb + SZ;
    short* Vt   = Kb + SZ;                          // [CB][DIM][SKL]
    short* Yb   = Vt + SZ;                          // ffn-LN out bf16
    short* FFb  = Qb;                               // [4096][768] aliases Qb..Vt
    short* Wqt  = Yb + SZ;
    short* Wkt  = Wqt + (size_t)NL * DIM * DIM;
    short* Wvt  = Wkt + (size_t)NL * DIM * DIM;
    short* Wot  = Wvt + (size_t)NL * DIM * DIM;
    short* W1t  = Wot + (size_t)NL * DIM * DIM;     // [L][768][256]
    short* W2t  = W1t + (size_t)NL * DIM * FFD;     // [L][256][768]

    {
        int total = CB * SQL * DIM;
        init_kernel<<<(total + 255) / 256, 256, 0, stream>>>(pose, vel, img, X, Xb, KVb);
    }
    transpose_qkvo<<<dim3(4, 4, 16), 256, 0, stream>>>(Wq, Wk, Wv, Wo, Wqt, Wkt, Wvt, Wot);
    transpose_w<<<dim3(FFD / 64, DIM / 64, NL), 256, 0, stream>>>(W1, W1t, DIM, FFD);
    transpose_w<<<dim3(DIM / 64, FFD / 64, NL), 256, 0, stream>>>(W2, W2t, FFD, DIM);

    const float qscale = 0.08838834764831845f;      // 0.5 / sqrt(32)

    for (int i = 0; i < NL; i++) {
        const short* Wqt_i = Wqt + (size_t)i * DIM * DIM;
        const short* Wkt_i = Wkt + (size_t)i * DIM * DIM;
        const short* Wvt_i = Wvt + (size_t)i * DIM * DIM;
        const short* Wot_i = Wot + (size_t)i * DIM * DIM;
        const short* W1t_i = W1t + (size_t)i * DIM * FFD;
        const short* W2t_i = W2t + (size_t)i * DIM * FFD;

        qkv_gemm<<<dim3(DIM / 64, ROWS / 64, 3), 256, 0, stream>>>(
            Xb, KVb, Wqt_i, Wkt_i, Wvt_i,
            bq + i * DIM, bk + i * DIM, bv + i * DIM, Qb, Kb, Vt, qscale);

        attn_mfma<<<dim3(SQL / 16, NH, CB), 256, 0, stream>>>(Qb, Kb, Vt, T1b);

        gemm_ln2<<<ROWS / 16, 256, 0, stream>>>(
            T1b, Wot_i, bo + i * DIM, X,
            an_g + i * DIM, an_b + i * DIM, fn_g + i * DIM, fn_b + i * DIM,
            X1b, Yb);

        gemm_mish<<<dim3(FFD / 64, ROWS / 64), 256, 0, stream>>>(
            Yb, W1t_i, b1 + i * FFD, FFb);

        float* outp  = (i == NL - 1) ? (float*)d_out : X;
        short* outbp = (i == NL - 1) ? nullptr : Xb;
        gemm_lnf<<<ROWS / 16, 256, 0, stream>>>(
            FFb, W2t_i, b2 + i * DIM, X1b, X,
            n_g + i * DIM, n_b + i * DIM, outp, outbp);
    }

    (void)in_sizes; (void)n_in; (void)out_size; (void)ws_size;
}

// Round 6
// 457.287 us; speedup vs baseline: 19.1222x; 1.2343x over previous
//
#include <hip/hip_runtime.h>
#include <math.h>

#define NL   4
#define DIM  256
#define NH   8
#define HDIM 32
#define SQL  1024
#define SKL  1024
#define FFD  768
#define CB   4              // combined batch: 2 stacks * 2 batch
#define ROWS (CB * SQL)     // 4096

typedef __attribute__((ext_vector_type(8))) short bf16x8;
typedef __attribute__((ext_vector_type(4))) short bf16x4;
typedef __attribute__((ext_vector_type(4))) float f32x4;
typedef __attribute__((ext_vector_type(2))) float f32x2;

// ---------------------------------------------------------------- utilities

__device__ __forceinline__ short f2bf(float f) {
    union { float f; unsigned u; } v; v.f = f;
    unsigned u = v.u + 0x7fffu + ((v.u >> 16) & 1u);   // RNE
    return (short)(u >> 16);
}

// mish(x) = x*tanh(softplus(x)) = x*(u^2+2u)/(u^2+2u+2), u = e^x.
// clamp exp arg at 20 so u^2 stays finite; ratio==1 there anyway.
__device__ __forceinline__ float fast_mish(float x) {
    float u = __expf(fminf(x, 20.0f));
    float a = __builtin_fmaf(u, u, 2.0f * u);          // u^2 + 2u
    return x * a * __builtin_amdgcn_rcpf(a + 2.0f);
}

__device__ __forceinline__ f32x2 lo2(f32x4 v) { return __builtin_shufflevector(v, v, 0, 1); }
__device__ __forceinline__ f32x2 hi2(f32x4 v) { return __builtin_shufflevector(v, v, 2, 3); }

// ---------------------------------------------------------------- init

__global__ __launch_bounds__(256) void init_kernel(
        const float* __restrict__ pose, const float* __restrict__ vel,
        const float* __restrict__ img, float* __restrict__ X,
        short* __restrict__ Xb, short* __restrict__ KVb) {
    int idx = blockIdx.x * 256 + threadIdx.x;
    if (idx >= CB * SQL * DIM) return;
    int c = idx / (SQL * DIM);
    int rem = idx - c * (SQL * DIM);
    int b = c & 1;
    float pv = pose[b * SQL * DIM + rem];
    X[idx]  = pv;
    Xb[idx] = f2bf(pv);
    const float* kv = (c < 2) ? vel : img;
    KVb[idx] = f2bf(kv[b * SQL * DIM + rem]);
}

// ---------------------------------------------------------------- weight transposes

__global__ __launch_bounds__(256) void transpose_qkvo(
        const float* __restrict__ Wq, const float* __restrict__ Wk,
        const float* __restrict__ Wv, const float* __restrict__ Wo,
        short* __restrict__ Wqt, short* __restrict__ Wkt,
        short* __restrict__ Wvt, short* __restrict__ Wot) {
    __shared__ float tile[64][65];
    int z = blockIdx.z, m = z >> 2, lyr = z & 3;
    const float* src = ((m == 0) ? Wq : (m == 1) ? Wk : (m == 2) ? Wv : Wo)
                       + (size_t)lyr * DIM * DIM;
    short* dst = ((m == 0) ? Wqt : (m == 1) ? Wkt : (m == 2) ? Wvt : Wot)
                 + (size_t)lyr * DIM * DIM;
    int t = threadIdx.x;
    int n0 = blockIdx.x * 64, k0 = blockIdx.y * 64;
#pragma unroll
    for (int i = 0; i < 16; i++) {
        int idx = t + i * 256;
        int r = idx >> 6, c = idx & 63;
        tile[r][c] = src[(size_t)(k0 + r) * DIM + n0 + c];
    }
    __syncthreads();
#pragma unroll
    for (int i = 0; i < 16; i++) {
        int idx = t + i * 256;
        int r = idx >> 6, c = idx & 63;
        dst[(size_t)(n0 + r) * DIM + k0 + c] = f2bf(tile[c][r]);
    }
}

__global__ __launch_bounds__(256) void transpose_w(
        const float* __restrict__ src, short* __restrict__ dst, int K, int N) {
    __shared__ float tile[64][65];
    int t = threadIdx.x;
    int n0 = blockIdx.x * 64, k0 = blockIdx.y * 64;
    const float* s = src + (size_t)blockIdx.z * K * N;
    short* d = dst + (size_t)blockIdx.z * K * N;
#pragma unroll
    for (int i = 0; i < 16; i++) {
        int idx = t + i * 256;
        int r = idx >> 6, c = idx & 63;
        tile[r][c] = s[(size_t)(k0 + r) * N + n0 + c];
    }
    __syncthreads();
#pragma unroll
    for (int i = 0; i < 16; i++) {
        int idx = t + i * 256;
        int r = idx >> 6, c = idx & 63;
        d[(size_t)(n0 + r) * K + k0 + c] = f2bf(tile[c][r]);
    }
}

// ---------------------------------------------------------------- QKV batched GEMM
// grid (DIM/64, ROWS/64, 3): z=0 Q (scaled), z=1 K, z=2 V (transposed out)

__global__ __launch_bounds__(256) void qkv_gemm(
        const short* __restrict__ Xb, const short* __restrict__ KVb,
        const short* __restrict__ Wqt, const short* __restrict__ Wkt,
        const short* __restrict__ Wvt,
        const float* __restrict__ bq, const float* __restrict__ bk,
        const float* __restrict__ bv,
        short* __restrict__ Qb, short* __restrict__ Kb, short* __restrict__ Vt,
        float qscale) {
    int z = blockIdx.z;
    const short* A    = (z == 0) ? Xb : KVb;
    const short* Wt   = (z == 0) ? Wqt : (z == 1) ? Wkt : Wvt;
    const float* bias = (z == 0) ? bq : (z == 1) ? bk : bv;
    float scale = (z == 0) ? qscale : 1.0f;

    int t = threadIdx.x, l = t & 63, w = t >> 6;
    int lq = l & 15, lg = l >> 4;
    int bm = blockIdx.y * 64, bn = blockIdx.x * 64;

    const short* ap = A + (size_t)(bm + w * 16 + lq) * DIM + lg * 8;
    const short* wp = Wt + (size_t)(bn + lq) * DIM + lg * 8;

    f32x4 acc[4];
#pragma unroll
    for (int nt = 0; nt < 4; nt++) acc[nt] = (f32x4){0.f, 0.f, 0.f, 0.f};
#pragma unroll
    for (int k0 = 0; k0 < DIM; k0 += 32) {
        bf16x8 af = *(const bf16x8*)(ap + k0);
#pragma unroll
        for (int nt = 0; nt < 4; nt++) {
            bf16x8 bfr = *(const bf16x8*)(wp + (size_t)nt * 16 * DIM + k0);
            acc[nt] = __builtin_amdgcn_mfma_f32_16x16x32_bf16(af, bfr, acc[nt], 0, 0, 0);
        }
    }

    int ms = bm + w * 16 + lg * 4;
#pragma unroll
    for (int nt = 0; nt < 4; nt++) {
        int col = bn + nt * 16 + lq;
        float bv_ = bias[col];
        float v[4];
#pragma unroll
        for (int j = 0; j < 4; j++) v[j] = acc[nt][j] + bv_;
        if (z < 2) {
            short* out = (z == 0) ? Qb : Kb;
#pragma unroll
            for (int j = 0; j < 4; j++) out[(size_t)(ms + j) * DIM + col] = f2bf(v[j] * scale);
        } else {
            int cc = ms >> 10, kl = ms & 1023;
            bf16x4 pk;
#pragma unroll
            for (int j = 0; j < 4; j++) pk[j] = f2bf(v[j]);
            *(bf16x4*)(Vt + ((size_t)(cc * DIM + col)) * SKL + kl) = pk;
        }
    }
}

// ---------------------------------------------------------------- GEMM + double LN
// G = A@Wo + bo; x1 = X + LN(G)*ag+ab; y = LN(x1)*fg+fb. grid (ROWS/16).

__global__ __launch_bounds__(256) void gemm_ln2(
        const short* __restrict__ A, const short* __restrict__ Wt,
        const float* __restrict__ bias, const float* __restrict__ Xres,
        const float* __restrict__ ag, const float* __restrict__ ab,
        const float* __restrict__ fg, const float* __restrict__ fb,
        float* __restrict__ x1out, short* __restrict__ yout) {
    __shared__ float gbuf[16][264];
    int t = threadIdx.x, l = t & 63, w = t >> 6;
    int lq = l & 15, lg = l >> 4;
    int bm = blockIdx.x * 16;

    const short* ap = A + (size_t)(bm + lq) * DIM + lg * 8;
    const short* wp = Wt + (size_t)(w * 64 + lq) * DIM + lg * 8;

    f32x4 acc[4];
#pragma unroll
    for (int nt = 0; nt < 4; nt++) acc[nt] = (f32x4){0.f, 0.f, 0.f, 0.f};
#pragma unroll
    for (int k0 = 0; k0 < DIM; k0 += 32) {
        bf16x8 af = *(const bf16x8*)(ap + k0);
#pragma unroll
        for (int nt = 0; nt < 4; nt++) {
            bf16x8 bfr = *(const bf16x8*)(wp + (size_t)nt * 16 * DIM + k0);
            acc[nt] = __builtin_amdgcn_mfma_f32_16x16x32_bf16(af, bfr, acc[nt], 0, 0, 0);
        }
    }
#pragma unroll
    for (int nt = 0; nt < 4; nt++) {
        int col = w * 64 + nt * 16 + lq;
        float bv_ = bias[col];
#pragma unroll
        for (int j = 0; j < 4; j++) gbuf[lg * 4 + j][col] = acc[nt][j] + bv_;
    }
    __syncthreads();

    int g = t >> 4, u = t & 15;
    int row = bm + g;
    float s = 0.f, s2 = 0.f;
#pragma unroll
    for (int i = 0; i < 16; i++) {
        float v = gbuf[g][u + 16 * i];
        s += v; s2 += v * v;
    }
#pragma unroll
    for (int off = 1; off < 16; off <<= 1) { s += __shfl_xor(s, off); s2 += __shfl_xor(s2, off); }
    float m = s * (1.f / DIM);
    float rstd = rsqrtf(s2 * (1.f / DIM) - m * m + 1e-5f);

    float x1v[16];
    float sb = 0.f, sb2 = 0.f;
#pragma unroll
    for (int i = 0; i < 16; i++) {
        int col = u + 16 * i;
        float x1 = Xres[(size_t)row * DIM + col] + (gbuf[g][col] - m) * rstd * ag[col] + ab[col];
        x1v[i] = x1; sb += x1; sb2 += x1 * x1;
    }
#pragma unroll
    for (int off = 1; off < 16; off <<= 1) { sb += __shfl_xor(sb, off); sb2 += __shfl_xor(sb2, off); }
    float m2 = sb * (1.f / DIM);
    float rstd2 = rsqrtf(sb2 * (1.f / DIM) - m2 * m2 + 1e-5f);
#pragma unroll
    for (int i = 0; i < 16; i++) {
        int col = u + 16 * i;
        x1out[(size_t)row * DIM + col] = x1v[i];
        yout[(size_t)row * DIM + col]  = f2bf((x1v[i] - m2) * rstd2 * fg[col] + fb[col]);
    }
}

// ---------------------------------------------------------------- fused FFN
// G1 = mish(Y@W1+b1) -> LDS bf16 [16][776]; x2 = G1@W2+b2+x1;
// out = X + LN(x2)*g+b. grid (ROWS/16), 256 thr.

__global__ __launch_bounds__(256) void gemm_ffn(
        const short* __restrict__ Yb, const short* __restrict__ W1t,
        const float* __restrict__ b1, const short* __restrict__ W2t,
        const float* __restrict__ b2, const float* __restrict__ x1res,
        const float* __restrict__ Xres, const float* __restrict__ g_,
        const float* __restrict__ b_,
        float* __restrict__ outf, short* __restrict__ outb) {
    __shared__ __align__(16) char lds[16 * 776 * 2];       // 24.8 KB
    short (*g1)[776]  = (short(*)[776])lds;
    float (*gbuf)[264] = (float(*)[264])lds;               // aliased after phase 2

    int t = threadIdx.x, l = t & 63, w = t >> 6;
    int lq = l & 15, lg = l >> 4;
    int bm = blockIdx.x * 16;

    // ---- phase 1: wave w computes cols [192w, 192w+192) of mish(Y@W1+b1)
    {
        const short* ap = Yb + (size_t)(bm + lq) * DIM + lg * 8;
        const short* wp = W1t + (size_t)(w * 192 + lq) * DIM + lg * 8;
        f32x4 acc[12];
#pragma unroll
        for (int nt = 0; nt < 12; nt++) acc[nt] = (f32x4){0.f, 0.f, 0.f, 0.f};
#pragma unroll
        for (int k0 = 0; k0 < DIM; k0 += 32) {
            bf16x8 af = *(const bf16x8*)(ap + k0);
#pragma unroll
            for (int nt = 0; nt < 12; nt++) {
                bf16x8 bfr = *(const bf16x8*)(wp + (size_t)nt * 16 * DIM + k0);
                acc[nt] = __builtin_amdgcn_mfma_f32_16x16x32_bf16(af, bfr, acc[nt], 0, 0, 0);
            }
        }
#pragma unroll
        for (int nt = 0; nt < 12; nt++) {
            int col = w * 192 + nt * 16 + lq;
            float bv_ = b1[col];
#pragma unroll
            for (int j = 0; j < 4; j++)
                g1[lg * 4 + j][col] = f2bf(fast_mish(acc[nt][j] + bv_));
        }
    }
    __syncthreads();

    // ---- phase 2: wave w computes cols [64w, 64w+64) of G1@W2, K=768
    f32x4 acc2[4];
#pragma unroll
    for (int nt = 0; nt < 4; nt++) acc2[nt] = (f32x4){0.f, 0.f, 0.f, 0.f};
    {
        const short* wp2 = W2t + (size_t)(w * 64 + lq) * FFD + lg * 8;
#pragma unroll 6
        for (int ks = 0; ks < 24; ks++) {
            bf16x8 af = *(const bf16x8*)(&g1[lq][ks * 32 + lg * 8]);
#pragma unroll
            for (int nt = 0; nt < 4; nt++) {
                bf16x8 bfr = *(const bf16x8*)(wp2 + (size_t)nt * 16 * FFD + ks * 32);
                acc2[nt] = __builtin_amdgcn_mfma_f32_16x16x32_bf16(af, bfr, acc2[nt], 0, 0, 0);
            }
        }
    }
    __syncthreads();   // done reading g1; gbuf may alias now

#pragma unroll
    for (int nt = 0; nt < 4; nt++) {
        int col = w * 64 + nt * 16 + lq;
        float bv_ = b2[col];
#pragma unroll
        for (int j = 0; j < 4; j++) {
            int row = bm + lg * 4 + j;
            gbuf[lg * 4 + j][col] = acc2[nt][j] + bv_ + x1res[(size_t)row * DIM + col];
        }
    }
    __syncthreads();

    int g = t >> 4, u = t & 15;
    int row = bm + g;
    float s = 0.f, s2 = 0.f;
#pragma unroll
    for (int i = 0; i < 16; i++) {
        float v = gbuf[g][u + 16 * i];
        s += v; s2 += v * v;
    }
#pragma unroll
    for (int off = 1; off < 16; off <<= 1) { s += __shfl_xor(s, off); s2 += __shfl_xor(s2, off); }
    float m = s * (1.f / DIM);
    float rstd = rsqrtf(s2 * (1.f / DIM) - m * m + 1e-5f);
#pragma unroll
    for (int i = 0; i < 16; i++) {
        int col = u + 16 * i;
        float o = Xres[(size_t)row * DIM + col] + (gbuf[g][col] - m) * rstd * g_[col] + b_[col];
        outf[(size_t)row * DIM + col] = o;
        if (outb) outb[(size_t)row * DIM + col] = f2bf(o);
    }
}

// ---------------------------------------------------------------- attention
// MFMA QK^T/PV + packed-math Michelot entmax-1.5 (no compares, no max-shift).
// grid (SQL/16, NH, CB), 256 threads = 4 waves; wave w owns k in [256w, 256w+256).

__global__ __launch_bounds__(256) void attn_mfma(
        const short* __restrict__ Q, const short* __restrict__ K,
        const short* __restrict__ Vt, short* __restrict__ O) {
    int h = blockIdx.y, c = blockIdx.z;
    int qbase = blockIdx.x * 16;
    int t = threadIdx.x, l = t & 63, w = t >> 6;
    int lq = l & 15, lg = l >> 4;

    __shared__ __align__(16) short p_lds[16 * 1024];   // [q][k] bf16, XOR-swizzled
    __shared__ float redf[3][4][16];
    float* obuf = (float*)p_lds;                       // aliased after barrier

    bf16x8 qfrag = *(const bf16x8*)(Q + ((size_t)(c * SQL + qbase + lq)) * DIM + h * HDIM + lg * 8);

    // ---- QK^T: acc[kt][j] = S[k = 256w+16kt+4lg+j][q=lq]
    const int kw = w * 256;
    f32x4 acc[16];
#pragma unroll
    for (int kt = 0; kt < 16; kt++) {
        bf16x8 kf = *(const bf16x8*)(K + ((size_t)(c * SKL + kw + kt * 16 + lq)) * DIM + h * HDIM + lg * 8);
        f32x4 z = {0.f, 0.f, 0.f, 0.f};
        acc[kt] = __builtin_amdgcn_mfma_f32_16x16x32_bf16(kf, qfrag, z, 0, 0, 0);
    }

    const f32x2 z2  = {0.f, 0.f};
    const f32x2 big = {1e30f, 1e30f};
    const f32x2 one = {1.f, 1.f};

    // ---- row max (packed tree; no shift of scores needed)
    f32x2 mm = lo2(acc[0]);
#pragma unroll
    for (int kt = 0; kt < 16; kt++) {
        mm = __builtin_elementwise_max(mm, lo2(acc[kt]));
        mm = __builtin_elementwise_max(mm, hi2(acc[kt]));
    }
    float m = fmaxf(mm.x, mm.y);
    m = fmaxf(m, __shfl_xor(m, 16));
    m = fmaxf(m, __shfl_xor(m, 32));
    if (l < 16) redf[0][w][l] = m;
    __syncthreads();
    m = fmaxf(fmaxf(redf[0][0][lq], redf[0][1][lq]),
              fmaxf(redf[0][2][lq], redf[0][3][lq]));

    // ---- Michelot: tau0 = m-1; per round: y = max(x-tau,0), exact quadratic
    // delta = (Sy - sqrt(Sy^2 - n(Sy2-1)))/n; tau* in [m-1, m-1/32].
    float tau = m - 1.0f;
#pragma unroll 1
    for (int r = 0; r < 5; r++) {
        f32x2 vt = {tau, tau};
        f32x2 S1 = z2, S2 = z2, NN = z2;
#pragma unroll
        for (int kt = 0; kt < 16; kt++) {
            f32x2 y0 = __builtin_elementwise_max(lo2(acc[kt]) - vt, z2);
            f32x2 y1 = __builtin_elementwise_max(hi2(acc[kt]) - vt, z2);
            S1 += y0; S1 += y1;
            S2 += y0 * y0; S2 += y1 * y1;
            NN += __builtin_elementwise_min(y0 * big, one);
            NN += __builtin_elementwise_min(y1 * big, one);
        }
        float sy = S1.x + S1.y, sy2 = S2.x + S2.y, nn = NN.x + NN.y;
        sy  += __shfl_xor(sy, 16);  sy  += __shfl_xor(sy, 32);
        sy2 += __shfl_xor(sy2, 16); sy2 += __shfl_xor(sy2, 32);
        nn  += __shfl_xor(nn, 16);  nn  += __shfl_xor(nn, 32);
        __syncthreads();
        if (l < 16) { redf[0][w][l] = nn; redf[1][w][l] = sy; redf[2][w][l] = sy2; }
        __syncthreads();
        nn  = redf[0][0][lq] + redf[0][1][lq] + redf[0][2][lq] + redf[0][3][lq];
        sy  = redf[1][0][lq] + redf[1][1][lq] + redf[1][2][lq] + redf[1][3][lq];
        sy2 = redf[2][0][lq] + redf[2][1][lq] + redf[2][2][lq] + redf[2][3][lq];
        float disc = fmaxf(sy * sy - nn * (sy2 - 1.0f), 0.f);
        tau = fminf(tau + (sy - sqrtf(disc)) / nn, m - 0.03125f);
    }

    // ---- p = clip(x-tau)^2 -> bf16 (packed cvt) -> swizzled LDS
    {
        f32x2 vt = {tau, tau};
#pragma unroll
        for (int kt = 0; kt < 16; kt++) {
            f32x2 y0 = __builtin_elementwise_max(lo2(acc[kt]) - vt, z2);
            f32x2 y1 = __builtin_elementwise_max(hi2(acc[kt]) - vt, z2);
            f32x2 p0 = y0 * y0, p1 = y1 * y1;
            unsigned u01, u23;
            asm("v_cvt_pk_bf16_f32 %0, %1, %2" : "=v"(u01) : "v"(p0.x), "v"(p0.y));
            asm("v_cvt_pk_bf16_f32 %0, %1, %2" : "=v"(u23) : "v"(p1.x), "v"(p1.y));
            int k = kw + kt * 16 + lg * 4;
            int byte = lq * 2048 + ((k * 2) ^ (lq << 4));
            *(uint2*)((char*)p_lds + byte) = make_uint2(u01, u23);
        }
    }
    __syncthreads();

    // ---- PV: wave sums its k-quarter; V frags contiguous from Vt [c][d][k]
    f32x4 o0 = {0.f, 0.f, 0.f, 0.f}, o1 = {0.f, 0.f, 0.f, 0.f};
#pragma unroll
    for (int kt2 = 0; kt2 < 8; kt2++) {
        int k0 = kw + kt2 * 32 + lg * 8;
        int byte = lq * 2048 + ((k0 * 2) ^ (lq << 4));
        bf16x8 pa = *(const bf16x8*)((const char*)p_lds + byte);
        bf16x8 vb0 = *(const bf16x8*)(Vt + ((size_t)(c * DIM + h * HDIM + lq)) * SKL + k0);
        bf16x8 vb1 = *(const bf16x8*)(Vt + ((size_t)(c * DIM + h * HDIM + 16 + lq)) * SKL + k0);
        o0 = __builtin_amdgcn_mfma_f32_16x16x32_bf16(pa, vb0, o0, 0, 0, 0);
        o1 = __builtin_amdgcn_mfma_f32_16x16x32_bf16(pa, vb1, o1, 0, 0, 0);
    }
    __syncthreads();

    // ---- cross-wave O reduce
#pragma unroll
    for (int j = 0; j < 4; j++) {
        obuf[w * 512 + (lg * 4 + j) * 32 + lq]      = o0[j];
        obuf[w * 512 + (lg * 4 + j) * 32 + 16 + lq] = o1[j];
    }
    __syncthreads();
#pragma unroll
    for (int rep = 0; rep < 2; rep++) {
        int e = t + rep * 256;
        int q = e >> 5, d = e & 31;
        float s = obuf[e] + obuf[512 + e] + obuf[1024 + e] + obuf[1536 + e];
        O[((size_t)(c * SQL + qbase + q)) * DIM + h * HDIM + d] = f2bf(s);
    }
}

// ---------------------------------------------------------------- driver

extern "C" void kernel_launch(void* const* d_in, const int* in_sizes, int n_in,
                              void* d_out, int out_size, void* d_ws, size_t ws_size,
                              hipStream_t stream) {
    const float* pose = (const float*)d_in[0];
    const float* vel  = (const float*)d_in[1];
    const float* img  = (const float*)d_in[2];
    const float* Wq   = (const float*)d_in[3];
    const float* bq   = (const float*)d_in[4];
    const float* Wk   = (const float*)d_in[5];
    const float* bk   = (const float*)d_in[6];
    const float* Wv   = (const float*)d_in[7];
    const float* bv   = (const float*)d_in[8];
    const float* Wo   = (const float*)d_in[9];
    const float* bo   = (const float*)d_in[10];
    const float* an_g = (const float*)d_in[11];
    const float* an_b = (const float*)d_in[12];
    const float* W1   = (const float*)d_in[13];
    const float* b1   = (const float*)d_in[14];
    const float* W2   = (const float*)d_in[15];
    const float* b2   = (const float*)d_in[16];
    const float* fn_g = (const float*)d_in[17];
    const float* fn_b = (const float*)d_in[18];
    const float* n_g  = (const float*)d_in[19];
    const float* n_b  = (const float*)d_in[20];

    const size_t SZ = (size_t)ROWS * DIM;           // 1M elements
    float* X    = (float*)d_ws;                     // fp32 residual stream
    float* X1b  = X + SZ;                           // fp32 x1
    short* Xb   = (short*)(X1b + SZ);
    short* KVb  = Xb + SZ;
    short* T1b  = KVb + SZ;                         // attn out bf16
    short* Qb   = T1b + SZ;
    short* Kb   = Qb + SZ;
    short* Vt   = Kb + SZ;                          // [CB][DIM][SKL]
    short* Yb   = Vt + SZ;                          // ffn-LN out bf16
    short* Wqt  = Yb + SZ;
    short* Wkt  = Wqt + (size_t)NL * DIM * DIM;
    short* Wvt  = Wkt + (size_t)NL * DIM * DIM;
    short* Wot  = Wvt + (size_t)NL * DIM * DIM;
    short* W1t  = Wot + (size_t)NL * DIM * DIM;     // [L][768][256]
    short* W2t  = W1t + (size_t)NL * DIM * FFD;     // [L][256][768]

    {
        int total = CB * SQL * DIM;
        init_kernel<<<(total + 255) / 256, 256, 0, stream>>>(pose, vel, img, X, Xb, KVb);
    }
    transpose_qkvo<<<dim3(4, 4, 16), 256, 0, stream>>>(Wq, Wk, Wv, Wo, Wqt, Wkt, Wvt, Wot);
    transpose_w<<<dim3(FFD / 64, DIM / 64, NL), 256, 0, stream>>>(W1, W1t, DIM, FFD);
    transpose_w<<<dim3(DIM / 64, FFD / 64, NL), 256, 0, stream>>>(W2, W2t, FFD, DIM);

    const float qscale = 0.08838834764831845f;      // 0.5 / sqrt(32)

    for (int i = 0; i < NL; i++) {
        const short* Wqt_i = Wqt + (size_t)i * DIM * DIM;
        const short* Wkt_i = Wkt + (size_t)i * DIM * DIM;
        const short* Wvt_i = Wvt + (size_t)i * DIM * DIM;
        const short* Wot_i = Wot + (size_t)i * DIM * DIM;
        const short* W1t_i = W1t + (size_t)i * DIM * FFD;
        const short* W2t_i = W2t + (size_t)i * DIM * FFD;

        qkv_gemm<<<dim3(DIM / 64, ROWS / 64, 3), 256, 0, stream>>>(
            Xb, KVb, Wqt_i, Wkt_i, Wvt_i,
            bq + i * DIM, bk + i * DIM, bv + i * DIM, Qb, Kb, Vt, qscale);

        attn_mfma<<<dim3(SQL / 16, NH, CB), 256, 0, stream>>>(Qb, Kb, Vt, T1b);

        gemm_ln2<<<ROWS / 16, 256, 0, stream>>>(
            T1b, Wot_i, bo + i * DIM, X,
            an_g + i * DIM, an_b + i * DIM, fn_g + i * DIM, fn_b + i * DIM,
            X1b, Yb);

        float* outp  = (i == NL - 1) ? (float*)d_out : X;
        short* outbp = (i == NL - 1) ? nullptr : Xb;
        gemm_ffn<<<ROWS / 16, 256, 0, stream>>>(
            Yb, W1t_i, b1 + i * FFD, W2t_i, b2 + i * DIM, X1b, X,
            n_g + i * DIM, n_b + i * DIM, outp, outbp);
    }

    (void)in_sizes; (void)n_in; (void)out_size; (void)ws_size;
}

// Round 7
// 415.207 us; speedup vs baseline: 21.0602x; 1.1013x over previous
//
#include <hip/hip_runtime.h>
#include <math.h>

#define NL   4
#define DIM  256
#define NH   8
#define HDIM 32
#define SQL  1024
#define SKL  1024
#define FFD  768
#define CB   4              // combined batch: 2 stacks * 2 batch
#define ROWS (CB * SQL)     // 4096

typedef __attribute__((ext_vector_type(8))) short bf16x8;
typedef __attribute__((ext_vector_type(4))) short bf16x4;
typedef __attribute__((ext_vector_type(4))) float f32x4;
typedef __attribute__((ext_vector_type(2))) float f32x2;

// ---------------------------------------------------------------- utilities

__device__ __forceinline__ short f2bf(float f) {
    union { float f; unsigned u; } v; v.f = f;
    unsigned u = v.u + 0x7fffu + ((v.u >> 16) & 1u);   // RNE
    return (short)(u >> 16);
}

// mish(x) = x*tanh(softplus(x)) = x*(u^2+2u)/(u^2+2u+2), u = e^x.
__device__ __forceinline__ float fast_mish(float x) {
    float u = __expf(fminf(x, 20.0f));
    float a = __builtin_fmaf(u, u, 2.0f * u);          // u^2 + 2u
    return x * a * __builtin_amdgcn_rcpf(a + 2.0f);
}

__device__ __forceinline__ f32x2 lo2(f32x4 v) { return __builtin_shufflevector(v, v, 0, 1); }
__device__ __forceinline__ f32x2 hi2(f32x4 v) { return __builtin_shufflevector(v, v, 2, 3); }

// ---------------------------------------------------------------- init

__global__ __launch_bounds__(256) void init_kernel(
        const float* __restrict__ pose, const float* __restrict__ vel,
        const float* __restrict__ img, float* __restrict__ X,
        short* __restrict__ Xb, short* __restrict__ KVb) {
    int idx = blockIdx.x * 256 + threadIdx.x;
    if (idx >= CB * SQL * DIM) return;
    int c = idx / (SQL * DIM);
    int rem = idx - c * (SQL * DIM);
    int b = c & 1;
    float pv = pose[b * SQL * DIM + rem];
    X[idx]  = pv;
    Xb[idx] = f2bf(pv);
    const float* kv = (c < 2) ? vel : img;
    KVb[idx] = f2bf(kv[b * SQL * DIM + rem]);
}

// ---------------------------------------------------------------- merged weight transpose
// 640 blocks: z<256 QKVO (4 mats x 4 layers x 16 tiles), z<448 W1, else W2.

__global__ __launch_bounds__(256) void transpose_all(
        const float* __restrict__ Wq, const float* __restrict__ Wk,
        const float* __restrict__ Wv, const float* __restrict__ Wo,
        const float* __restrict__ W1, const float* __restrict__ W2,
        short* __restrict__ Wqt, short* __restrict__ Wkt,
        short* __restrict__ Wvt, short* __restrict__ Wot,
        short* __restrict__ W1t, short* __restrict__ W2t) {
    __shared__ float tile[64][65];
    int z = blockIdx.x;
    const float* src; short* dst; int K, N, tx, ty;
    if (z < 256) {
        int m = z >> 6, lyr = (z >> 4) & 3, r = z & 15;
        src = ((m == 0) ? Wq : (m == 1) ? Wk : (m == 2) ? Wv : Wo) + (size_t)lyr * DIM * DIM;
        dst = ((m == 0) ? Wqt : (m == 1) ? Wkt : (m == 2) ? Wvt : Wot) + (size_t)lyr * DIM * DIM;
        K = DIM; N = DIM; tx = r & 3; ty = r >> 2;
    } else if (z < 448) {
        int idx = z - 256, lyr = idx / 48, r = idx % 48;
        src = W1 + (size_t)lyr * DIM * FFD; dst = W1t + (size_t)lyr * DIM * FFD;
        K = DIM; N = FFD; tx = r % 12; ty = r / 12;
    } else {
        int idx = z - 448, lyr = idx / 48, r = idx % 48;
        src = W2 + (size_t)lyr * FFD * DIM; dst = W2t + (size_t)lyr * FFD * DIM;
        K = FFD; N = DIM; tx = r % 4; ty = r / 4;
    }
    int t = threadIdx.x;
    int n0 = tx * 64, k0 = ty * 64;
#pragma unroll
    for (int i = 0; i < 16; i++) {
        int idx = t + i * 256;
        int r = idx >> 6, c = idx & 63;
        tile[r][c] = src[(size_t)(k0 + r) * N + n0 + c];
    }
    __syncthreads();
#pragma unroll
    for (int i = 0; i < 16; i++) {
        int idx = t + i * 256;
        int r = idx >> 6, c = idx & 63;
        dst[(size_t)(n0 + r) * K + k0 + c] = f2bf(tile[c][r]);
    }
}

// ---------------------------------------------------------------- QKV batched GEMM
// grid (DIM/64, ROWS/64, 3): z=0 Q (scaled), z=1 K, z=2 V (transposed out)

__global__ __launch_bounds__(256) void qkv_gemm(
        const short* __restrict__ Xb, const short* __restrict__ KVb,
        const short* __restrict__ Wqt, const short* __restrict__ Wkt,
        const short* __restrict__ Wvt,
        const float* __restrict__ bq, const float* __restrict__ bk,
        const float* __restrict__ bv,
        short* __restrict__ Qb, short* __restrict__ Kb, short* __restrict__ Vt,
        float qscale) {
    int z = blockIdx.z;
    const short* A    = (z == 0) ? Xb : KVb;
    const short* Wt   = (z == 0) ? Wqt : (z == 1) ? Wkt : Wvt;
    const float* bias = (z == 0) ? bq : (z == 1) ? bk : bv;
    float scale = (z == 0) ? qscale : 1.0f;

    int t = threadIdx.x, l = t & 63, w = t >> 6;
    int lq = l & 15, lg = l >> 4;
    int bm = blockIdx.y * 64, bn = blockIdx.x * 64;

    const short* ap = A + (size_t)(bm + w * 16 + lq) * DIM + lg * 8;
    const short* wp = Wt + (size_t)(bn + lq) * DIM + lg * 8;

    f32x4 acc[4];
#pragma unroll
    for (int nt = 0; nt < 4; nt++) acc[nt] = (f32x4){0.f, 0.f, 0.f, 0.f};
#pragma unroll
    for (int k0 = 0; k0 < DIM; k0 += 32) {
        bf16x8 af = *(const bf16x8*)(ap + k0);
#pragma unroll
        for (int nt = 0; nt < 4; nt++) {
            bf16x8 bfr = *(const bf16x8*)(wp + (size_t)nt * 16 * DIM + k0);
            acc[nt] = __builtin_amdgcn_mfma_f32_16x16x32_bf16(af, bfr, acc[nt], 0, 0, 0);
        }
    }

    int ms = bm + w * 16 + lg * 4;
#pragma unroll
    for (int nt = 0; nt < 4; nt++) {
        int col = bn + nt * 16 + lq;
        float bv_ = bias[col];
        float v[4];
#pragma unroll
        for (int j = 0; j < 4; j++) v[j] = acc[nt][j] + bv_;
        if (z < 2) {
            short* out = (z == 0) ? Qb : Kb;
#pragma unroll
            for (int j = 0; j < 4; j++) out[(size_t)(ms + j) * DIM + col] = f2bf(v[j] * scale);
        } else {
            int cc = ms >> 10, kl = ms & 1023;
            bf16x4 pk;
#pragma unroll
            for (int j = 0; j < 4; j++) pk[j] = f2bf(v[j]);
            *(bf16x4*)(Vt + ((size_t)(cc * DIM + col)) * SKL + kl) = pk;
        }
    }
}

// ---------------------------------------------------------------- GEMM + double LN (512 thr)
// G = A@Wo + bo; x1 = X + LN(G)*ag+ab; y = LN(x1)*fg+fb. grid (ROWS/16).

__global__ __launch_bounds__(512) void gemm_ln2(
        const short* __restrict__ A, const short* __restrict__ Wt,
        const float* __restrict__ bias, const float* __restrict__ Xres,
        const float* __restrict__ ag, const float* __restrict__ ab,
        const float* __restrict__ fg, const float* __restrict__ fb,
        float* __restrict__ x1out, short* __restrict__ yout) {
    __shared__ float gbuf[16][264];
    int t = threadIdx.x, l = t & 63, w = t >> 6;      // w: 0..7
    int lq = l & 15, lg = l >> 4;
    int bm = blockIdx.x * 16;

    const short* ap = A + (size_t)(bm + lq) * DIM + lg * 8;
    const short* wp = Wt + (size_t)(w * 32 + lq) * DIM + lg * 8;

    f32x4 acc[2];
    acc[0] = (f32x4){0.f, 0.f, 0.f, 0.f};
    acc[1] = (f32x4){0.f, 0.f, 0.f, 0.f};
#pragma unroll
    for (int k0 = 0; k0 < DIM; k0 += 32) {
        bf16x8 af = *(const bf16x8*)(ap + k0);
#pragma unroll
        for (int nt = 0; nt < 2; nt++) {
            bf16x8 bfr = *(const bf16x8*)(wp + (size_t)nt * 16 * DIM + k0);
            acc[nt] = __builtin_amdgcn_mfma_f32_16x16x32_bf16(af, bfr, acc[nt], 0, 0, 0);
        }
    }
#pragma unroll
    for (int nt = 0; nt < 2; nt++) {
        int col = w * 32 + nt * 16 + lq;
        float bv_ = bias[col];
#pragma unroll
        for (int j = 0; j < 4; j++) gbuf[lg * 4 + j][col] = acc[nt][j] + bv_;
    }
    __syncthreads();

    int g = t >> 5, u = t & 31;                        // 16 rows x 32 thr
    int row = bm + g;
    float s = 0.f, s2 = 0.f;
#pragma unroll
    for (int i = 0; i < 8; i++) {
        float v = gbuf[g][u + 32 * i];
        s += v; s2 += v * v;
    }
#pragma unroll
    for (int off = 1; off < 32; off <<= 1) { s += __shfl_xor(s, off); s2 += __shfl_xor(s2, off); }
    float m = s * (1.f / DIM);
    float rstd = rsqrtf(s2 * (1.f / DIM) - m * m + 1e-5f);

    float x1v[8];
    float sb = 0.f, sb2 = 0.f;
#pragma unroll
    for (int i = 0; i < 8; i++) {
        int col = u + 32 * i;
        float x1 = Xres[(size_t)row * DIM + col] + (gbuf[g][col] - m) * rstd * ag[col] + ab[col];
        x1v[i] = x1; sb += x1; sb2 += x1 * x1;
    }
#pragma unroll
    for (int off = 1; off < 32; off <<= 1) { sb += __shfl_xor(sb, off); sb2 += __shfl_xor(sb2, off); }
    float m2 = sb * (1.f / DIM);
    float rstd2 = rsqrtf(sb2 * (1.f / DIM) - m2 * m2 + 1e-5f);
#pragma unroll
    for (int i = 0; i < 8; i++) {
        int col = u + 32 * i;
        x1out[(size_t)row * DIM + col] = x1v[i];
        yout[(size_t)row * DIM + col]  = f2bf((x1v[i] - m2) * rstd2 * fg[col] + fb[col]);
    }
}

// ---------------------------------------------------------------- fused FFN (512 thr)
// G1 = mish(Y@W1+b1) -> LDS bf16 [16][776]; x2 = G1@W2+b2+x1;
// out = X + LN(x2)*g+b. grid (ROWS/16).

__global__ __launch_bounds__(512) void gemm_ffn(
        const short* __restrict__ Yb, const short* __restrict__ W1t,
        const float* __restrict__ b1, const short* __restrict__ W2t,
        const float* __restrict__ b2, const float* __restrict__ x1res,
        const float* __restrict__ Xres, const float* __restrict__ g_,
        const float* __restrict__ b_,
        float* __restrict__ outf, short* __restrict__ outb) {
    __shared__ __align__(16) char lds[16 * 776 * 2];       // 24.8 KB
    short (*g1)[776]   = (short(*)[776])lds;
    float (*gbuf)[264] = (float(*)[264])lds;               // aliased after phase 2

    int t = threadIdx.x, l = t & 63, w = t >> 6;           // w: 0..7
    int lq = l & 15, lg = l >> 4;
    int bm = blockIdx.x * 16;

    // ---- phase 1: wave w computes cols [96w, 96w+96) of mish(Y@W1+b1)
    {
        const short* ap = Yb + (size_t)(bm + lq) * DIM + lg * 8;
        const short* wp = W1t + (size_t)(w * 96 + lq) * DIM + lg * 8;
        f32x4 acc[6];
#pragma unroll
        for (int nt = 0; nt < 6; nt++) acc[nt] = (f32x4){0.f, 0.f, 0.f, 0.f};
#pragma unroll
        for (int k0 = 0; k0 < DIM; k0 += 32) {
            bf16x8 af = *(const bf16x8*)(ap + k0);
#pragma unroll
            for (int nt = 0; nt < 6; nt++) {
                bf16x8 bfr = *(const bf16x8*)(wp + (size_t)nt * 16 * DIM + k0);
                acc[nt] = __builtin_amdgcn_mfma_f32_16x16x32_bf16(af, bfr, acc[nt], 0, 0, 0);
            }
        }
#pragma unroll
        for (int nt = 0; nt < 6; nt++) {
            int col = w * 96 + nt * 16 + lq;
            float bv_ = b1[col];
#pragma unroll
            for (int j = 0; j < 4; j++)
                g1[lg * 4 + j][col] = f2bf(fast_mish(acc[nt][j] + bv_));
        }
    }
    __syncthreads();

    // ---- phase 2: wave w computes cols [32w, 32w+32) of G1@W2, K=768
    f32x4 acc2[2];
    acc2[0] = (f32x4){0.f, 0.f, 0.f, 0.f};
    acc2[1] = (f32x4){0.f, 0.f, 0.f, 0.f};
    {
        const short* wp2 = W2t + (size_t)(w * 32 + lq) * FFD + lg * 8;
#pragma unroll 6
        for (int ks = 0; ks < 24; ks++) {
            bf16x8 af = *(const bf16x8*)(&g1[lq][ks * 32 + lg * 8]);
#pragma unroll
            for (int nt = 0; nt < 2; nt++) {
                bf16x8 bfr = *(const bf16x8*)(wp2 + (size_t)nt * 16 * FFD + ks * 32);
                acc2[nt] = __builtin_amdgcn_mfma_f32_16x16x32_bf16(af, bfr, acc2[nt], 0, 0, 0);
            }
        }
    }
    __syncthreads();   // all g1 reads done; gbuf may alias now

#pragma unroll
    for (int nt = 0; nt < 2; nt++) {
        int col = w * 32 + nt * 16 + lq;
        float bv_ = b2[col];
#pragma unroll
        for (int j = 0; j < 4; j++) {
            int row = bm + lg * 4 + j;
            gbuf[lg * 4 + j][col] = acc2[nt][j] + bv_ + x1res[(size_t)row * DIM + col];
        }
    }
    __syncthreads();

    int g = t >> 5, u = t & 31;
    int row = bm + g;
    float s = 0.f, s2 = 0.f;
#pragma unroll
    for (int i = 0; i < 8; i++) {
        float v = gbuf[g][u + 32 * i];
        s += v; s2 += v * v;
    }
#pragma unroll
    for (int off = 1; off < 32; off <<= 1) { s += __shfl_xor(s, off); s2 += __shfl_xor(s2, off); }
    float m = s * (1.f / DIM);
    float rstd = rsqrtf(s2 * (1.f / DIM) - m * m + 1e-5f);
#pragma unroll
    for (int i = 0; i < 8; i++) {
        int col = u + 32 * i;
        float o = Xres[(size_t)row * DIM + col] + (gbuf[g][col] - m) * rstd * g_[col] + b_[col];
        outf[(size_t)row * DIM + col] = o;
        if (outb) outb[(size_t)row * DIM + col] = f2bf(o);
    }
}

// ---------------------------------------------------------------- attention
// MFMA QK^T/PV + packed Michelot entmax-1.5 with early exit.
// P chunked through wave-private LDS (no barriers); 18 KB LDS -> ~7 blocks/CU.
// grid (SQL/16, NH, CB), 256 threads = 4 waves; wave w owns k in [256w, 256w+256).

__global__ __launch_bounds__(256) void attn_mfma(
        const short* __restrict__ Q, const short* __restrict__ K,
        const short* __restrict__ Vt, short* __restrict__ O) {
    int h = blockIdx.y, c = blockIdx.z;
    int qbase = blockIdx.x * 16;
    int t = threadIdx.x, l = t & 63, w = t >> 6;
    int lq = l & 15, lg = l >> 4;

    __shared__ __align__(16) short p_lds[4][1024];     // wave-private [16 q][64 k] chunk
    __shared__ float obuf[4][512];                     // per-wave O partials [q][d]
    __shared__ float redf[2][3][4][16];                // double-buffered reductions

    bf16x8 qfrag = *(const bf16x8*)(Q + ((size_t)(c * SQL + qbase + lq)) * DIM + h * HDIM + lg * 8);

    // ---- QK^T: acc[kt][j] = S[k = 256w+16kt+4lg+j][q=lq]
    const int kw = w * 256;
    f32x4 acc[16];
#pragma unroll
    for (int kt = 0; kt < 16; kt++) {
        bf16x8 kf = *(const bf16x8*)(K + ((size_t)(c * SKL + kw + kt * 16 + lq)) * DIM + h * HDIM + lg * 8);
        f32x4 z = {0.f, 0.f, 0.f, 0.f};
        acc[kt] = __builtin_amdgcn_mfma_f32_16x16x32_bf16(kf, qfrag, z, 0, 0, 0);
    }

    const f32x2 z2  = {0.f, 0.f};
    const f32x2 big = {1e30f, 1e30f};
    const f32x2 one = {1.f, 1.f};

    // ---- row max (uses redf buffer 1; rounds start at buffer 0)
    f32x2 mm = lo2(acc[0]);
#pragma unroll
    for (int kt = 0; kt < 16; kt++) {
        mm = __builtin_elementwise_max(mm, lo2(acc[kt]));
        mm = __builtin_elementwise_max(mm, hi2(acc[kt]));
    }
    float m = fmaxf(mm.x, mm.y);
    m = fmaxf(m, __shfl_xor(m, 16));
    m = fmaxf(m, __shfl_xor(m, 32));
    if (l < 16) redf[1][0][w][l] = m;
    __syncthreads();
    m = fmaxf(fmaxf(redf[1][0][0][lq], redf[1][0][1][lq]),
              fmaxf(redf[1][0][2][lq], redf[1][0][3][lq]));

    // ---- Michelot from below: tau0 = m-1; exact quadratic per round;
    // early exit when converged for all rows (identical across waves -> uniform).
    float tau = m - 1.0f;
    int r = 0;
    for (;;) {
        f32x2 vt = {tau, tau};
        f32x2 S1 = z2, S2 = z2, NN = z2;
#pragma unroll
        for (int kt = 0; kt < 16; kt++) {
            f32x2 y0 = __builtin_elementwise_max(lo2(acc[kt]) - vt, z2);
            f32x2 y1 = __builtin_elementwise_max(hi2(acc[kt]) - vt, z2);
            S1 += y0; S1 += y1;
            S2 += y0 * y0; S2 += y1 * y1;
            NN += __builtin_elementwise_min(y0 * big, one);
            NN += __builtin_elementwise_min(y1 * big, one);
        }
        float sy = S1.x + S1.y, sy2 = S2.x + S2.y, nn = NN.x + NN.y;
        sy  += __shfl_xor(sy, 16);  sy  += __shfl_xor(sy, 32);
        sy2 += __shfl_xor(sy2, 16); sy2 += __shfl_xor(sy2, 32);
        nn  += __shfl_xor(nn, 16);  nn  += __shfl_xor(nn, 32);
        int b = r & 1;
        if (l < 16) { redf[b][0][w][l] = nn; redf[b][1][w][l] = sy; redf[b][2][w][l] = sy2; }
        __syncthreads();
        nn  = redf[b][0][0][lq] + redf[b][0][1][lq] + redf[b][0][2][lq] + redf[b][0][3][lq];
        sy  = redf[b][1][0][lq] + redf[b][1][1][lq] + redf[b][1][2][lq] + redf[b][1][3][lq];
        sy2 = redf[b][2][0][lq] + redf[b][2][1][lq] + redf[b][2][2][lq] + redf[b][2][3][lq];
        float disc = fmaxf(sy * sy - nn * (sy2 - 1.0f), 0.f);
        float delta = (sy - sqrtf(disc)) / nn;
        tau = fminf(tau + delta, m - 0.03125f);
        r++;
        if (r >= 6 || __all(delta < 1e-6f)) break;
    }

    // ---- PV in 4 chunks: p -> wave-private swizzled LDS -> MFMA (no barriers)
    f32x4 o0 = {0.f, 0.f, 0.f, 0.f}, o1 = {0.f, 0.f, 0.f, 0.f};
    const short* vbase0 = Vt + ((size_t)(c * DIM + h * HDIM + lq)) * SKL;
    const short* vbase1 = vbase0 + (size_t)16 * SKL;
    {
        f32x2 vt = {tau, tau};
        int swz = (lq & 7) << 4;
#pragma unroll
        for (int c2 = 0; c2 < 4; c2++) {
#pragma unroll
            for (int k4 = 0; k4 < 4; k4++) {
                int kt = c2 * 4 + k4;
                f32x2 y0 = __builtin_elementwise_max(lo2(acc[kt]) - vt, z2);
                f32x2 y1 = __builtin_elementwise_max(hi2(acc[kt]) - vt, z2);
                f32x2 p0 = y0 * y0, p1 = y1 * y1;
                unsigned u01, u23;
                asm("v_cvt_pk_bf16_f32 %0, %1, %2" : "=v"(u01) : "v"(p0.x), "v"(p0.y));
                asm("v_cvt_pk_bf16_f32 %0, %1, %2" : "=v"(u23) : "v"(p1.x), "v"(p1.y));
                int klocal = k4 * 16 + lg * 4;
                int byte = lq * 128 + ((klocal * 2) ^ swz);
                *(uint2*)((char*)p_lds[w] + byte) = make_uint2(u01, u23);
            }
#pragma unroll
            for (int k2 = 0; k2 < 2; k2++) {
                int klocal0 = k2 * 32 + lg * 8;
                int byte = lq * 128 + ((klocal0 * 2) ^ swz);
                bf16x8 pa = *(const bf16x8*)((const char*)p_lds[w] + byte);
                int k0 = kw + c2 * 64 + klocal0;
                bf16x8 vb0 = *(const bf16x8*)(vbase0 + k0);
                bf16x8 vb1 = *(const bf16x8*)(vbase1 + k0);
                o0 = __builtin_amdgcn_mfma_f32_16x16x32_bf16(pa, vb0, o0, 0, 0, 0);
                o1 = __builtin_amdgcn_mfma_f32_16x16x32_bf16(pa, vb1, o1, 0, 0, 0);
            }
        }
    }

    // ---- cross-wave O reduce
#pragma unroll
    for (int j = 0; j < 4; j++) {
        obuf[w][(lg * 4 + j) * 32 + lq]      = o0[j];
        obuf[w][(lg * 4 + j) * 32 + 16 + lq] = o1[j];
    }
    __syncthreads();
#pragma unroll
    for (int rep = 0; rep < 2; rep++) {
        int e = t + rep * 256;
        int q = e >> 5, d = e & 31;
        float s = obuf[0][e] + obuf[1][e] + obuf[2][e] + obuf[3][e];
        O[((size_t)(c * SQL + qbase + q)) * DIM + h * HDIM + d] = f2bf(s);
    }
}

// ---------------------------------------------------------------- driver

extern "C" void kernel_launch(void* const* d_in, const int* in_sizes, int n_in,
                              void* d_out, int out_size, void* d_ws, size_t ws_size,
                              hipStream_t stream) {
    const float* pose = (const float*)d_in[0];
    const float* vel  = (const float*)d_in[1];
    const float* img  = (const float*)d_in[2];
    const float* Wq   = (const float*)d_in[3];
    const float* bq   = (const float*)d_in[4];
    const float* Wk   = (const float*)d_in[5];
    const float* bk   = (const float*)d_in[6];
    const float* Wv   = (const float*)d_in[7];
    const float* bv   = (const float*)d_in[8];
    const float* Wo   = (const float*)d_in[9];
    const float* bo   = (const float*)d_in[10];
    const float* an_g = (const float*)d_in[11];
    const float* an_b = (const float*)d_in[12];
    const float* W1   = (const float*)d_in[13];
    const float* b1   = (const float*)d_in[14];
    const float* W2   = (const float*)d_in[15];
    const float* b2   = (const float*)d_in[16];
    const float* fn_g = (const float*)d_in[17];
    const float* fn_b = (const float*)d_in[18];
    const float* n_g  = (const float*)d_in[19];
    const float* n_b  = (const float*)d_in[20];

    const size_t SZ = (size_t)ROWS * DIM;           // 1M elements
    float* X    = (float*)d_ws;                     // fp32 residual stream
    float* X1b  = X + SZ;                           // fp32 x1
    short* Xb   = (short*)(X1b + SZ);
    short* KVb  = Xb + SZ;
    short* T1b  = KVb + SZ;                         // attn out bf16
    short* Qb   = T1b + SZ;
    short* Kb   = Qb + SZ;
    short* Vt   = Kb + SZ;                          // [CB][DIM][SKL]
    short* Yb   = Vt + SZ;                          // ffn-LN out bf16
    short* Wqt  = Yb + SZ;
    short* Wkt  = Wqt + (size_t)NL * DIM * DIM;
    short* Wvt  = Wkt + (size_t)NL * DIM * DIM;
    short* Wot  = Wvt + (size_t)NL * DIM * DIM;
    short* W1t  = Wot + (size_t)NL * DIM * DIM;     // [L][768][256]
    short* W2t  = W1t + (size_t)NL * DIM * FFD;     // [L][256][768]

    {
        int total = CB * SQL * DIM;
        init_kernel<<<(total + 255) / 256, 256, 0, stream>>>(pose, vel, img, X, Xb, KVb);
    }
    transpose_all<<<640, 256, 0, stream>>>(Wq, Wk, Wv, Wo, W1, W2,
                                           Wqt, Wkt, Wvt, Wot, W1t, W2t);

    const float qscale = 0.08838834764831845f;      // 0.5 / sqrt(32)

    for (int i = 0; i < NL; i++) {
        const short* Wqt_i = Wqt + (size_t)i * DIM * DIM;
        const short* Wkt_i = Wkt + (size_t)i * DIM * DIM;
        const short* Wvt_i = Wvt + (size_t)i * DIM * DIM;
        const short* Wot_i = Wot + (size_t)i * DIM * DIM;
        const short* W1t_i = W1t + (size_t)i * DIM * FFD;
        const short* W2t_i = W2t + (size_t)i * DIM * FFD;

        qkv_gemm<<<dim3(DIM / 64, ROWS / 64, 3), 256, 0, stream>>>(
            Xb, KVb, Wqt_i, Wkt_i, Wvt_i,
            bq + i * DIM, bk + i * DIM, bv + i * DIM, Qb, Kb, Vt, qscale);

        attn_mfma<<<dim3(SQL / 16, NH, CB), 256, 0, stream>>>(Qb, Kb, Vt, T1b);

        gemm_ln2<<<ROWS / 16, 512, 0, stream>>>(
            T1b, Wot_i, bo + i * DIM, X,
            an_g + i * DIM, an_b + i * DIM, fn_g + i * DIM, fn_b + i * DIM,
            X1b, Yb);

        float* outp  = (i == NL - 1) ? (float*)d_out : X;
        short* outbp = (i == NL - 1) ? nullptr : Xb;
        gemm_ffn<<<ROWS / 16, 512, 0, stream>>>(
            Yb, W1t_i, b1 + i * FFD, W2t_i, b2 + i * DIM, X1b, X,
            n_g + i * DIM, n_b + i * DIM, outp, outbp);
    }

    (void)in_sizes; (void)n_in; (void)out_size; (void)ws_size;
}

// Round 8
// 388.464 us; speedup vs baseline: 22.5100x; 1.0688x over previous
//
#include <hip/hip_runtime.h>
#include <math.h>

#define NL   4
#define DIM  256
#define NH   8
#define HDIM 32
#define SQL  1024
#define SKL  1024
#define FFD  768
#define CB   4              // combined batch: 2 stacks * 2 batch
#define ROWS (CB * SQL)     // 4096

typedef __attribute__((ext_vector_type(8))) short bf16x8;
typedef __attribute__((ext_vector_type(4))) short bf16x4;
typedef __attribute__((ext_vector_type(4))) float f32x4;
typedef __attribute__((ext_vector_type(2))) float f32x2;

// ---------------------------------------------------------------- utilities

__device__ __forceinline__ short f2bf(float f) {
    union { float f; unsigned u; } v; v.f = f;
    unsigned u = v.u + 0x7fffu + ((v.u >> 16) & 1u);   // RNE
    return (short)(u >> 16);
}

// mish(x) = x*tanh(softplus(x)) = x*(u^2+2u)/(u^2+2u+2), u = e^x.
__device__ __forceinline__ float fast_mish(float x) {
    float u = __expf(fminf(x, 20.0f));
    float a = __builtin_fmaf(u, u, 2.0f * u);          // u^2 + 2u
    return x * a * __builtin_amdgcn_rcpf(a + 2.0f);
}

__device__ __forceinline__ f32x2 lo2(f32x4 v) { return __builtin_shufflevector(v, v, 0, 1); }
__device__ __forceinline__ f32x2 hi2(f32x4 v) { return __builtin_shufflevector(v, v, 2, 3); }

// ---------------------------------------------------------------- init

__global__ __launch_bounds__(256) void init_kernel(
        const float* __restrict__ pose, const float* __restrict__ vel,
        const float* __restrict__ img, float* __restrict__ X,
        short* __restrict__ Xb, short* __restrict__ KVb) {
    int idx = blockIdx.x * 256 + threadIdx.x;
    if (idx >= CB * SQL * DIM) return;
    int c = idx / (SQL * DIM);
    int rem = idx - c * (SQL * DIM);
    int b = c & 1;
    float pv = pose[b * SQL * DIM + rem];
    X[idx]  = pv;
    Xb[idx] = f2bf(pv);
    const float* kv = (c < 2) ? vel : img;
    KVb[idx] = f2bf(kv[b * SQL * DIM + rem]);
}

// ---------------------------------------------------------------- merged weight transpose
// 640 blocks: z<256 QKVO (4 mats x 4 layers x 16 tiles), z<448 W1, else W2.

__global__ __launch_bounds__(256) void transpose_all(
        const float* __restrict__ Wq, const float* __restrict__ Wk,
        const float* __restrict__ Wv, const float* __restrict__ Wo,
        const float* __restrict__ W1, const float* __restrict__ W2,
        short* __restrict__ Wqt, short* __restrict__ Wkt,
        short* __restrict__ Wvt, short* __restrict__ Wot,
        short* __restrict__ W1t, short* __restrict__ W2t) {
    __shared__ float tile[64][65];
    int z = blockIdx.x;
    const float* src; short* dst; int K, N, tx, ty;
    if (z < 256) {
        int m = z >> 6, lyr = (z >> 4) & 3, r = z & 15;
        src = ((m == 0) ? Wq : (m == 1) ? Wk : (m == 2) ? Wv : Wo) + (size_t)lyr * DIM * DIM;
        dst = ((m == 0) ? Wqt : (m == 1) ? Wkt : (m == 2) ? Wvt : Wot) + (size_t)lyr * DIM * DIM;
        K = DIM; N = DIM; tx = r & 3; ty = r >> 2;
    } else if (z < 448) {
        int idx = z - 256, lyr = idx / 48, r = idx % 48;
        src = W1 + (size_t)lyr * DIM * FFD; dst = W1t + (size_t)lyr * DIM * FFD;
        K = DIM; N = FFD; tx = r % 12; ty = r / 12;
    } else {
        int idx = z - 448, lyr = idx / 48, r = idx % 48;
        src = W2 + (size_t)lyr * FFD * DIM; dst = W2t + (size_t)lyr * FFD * DIM;
        K = FFD; N = DIM; tx = r % 4; ty = r / 4;
    }
    int t = threadIdx.x;
    int n0 = tx * 64, k0 = ty * 64;
#pragma unroll
    for (int i = 0; i < 16; i++) {
        int idx = t + i * 256;
        int r = idx >> 6, c = idx & 63;
        tile[r][c] = src[(size_t)(k0 + r) * N + n0 + c];
    }
    __syncthreads();
#pragma unroll
    for (int i = 0; i < 16; i++) {
        int idx = t + i * 256;
        int r = idx >> 6, c = idx & 63;
        dst[(size_t)(n0 + r) * K + k0 + c] = f2bf(tile[c][r]);
    }
}

// ---------------------------------------------------------------- QKV batched GEMM
// grid (DIM/64, ROWS/64, 3): z=0 Q (scaled), z=1 K, z=2 V (transposed out)

__global__ __launch_bounds__(256) void qkv_gemm(
        const short* __restrict__ Xb, const short* __restrict__ KVb,
        const short* __restrict__ Wqt, const short* __restrict__ Wkt,
        const short* __restrict__ Wvt,
        const float* __restrict__ bq, const float* __restrict__ bk,
        const float* __restrict__ bv,
        short* __restrict__ Qb, short* __restrict__ Kb, short* __restrict__ Vt,
        float qscale) {
    int z = blockIdx.z;
    const short* A    = (z == 0) ? Xb : KVb;
    const short* Wt   = (z == 0) ? Wqt : (z == 1) ? Wkt : Wvt;
    const float* bias = (z == 0) ? bq : (z == 1) ? bk : bv;
    float scale = (z == 0) ? qscale : 1.0f;

    int t = threadIdx.x, l = t & 63, w = t >> 6;
    int lq = l & 15, lg = l >> 4;
    int bm = blockIdx.y * 64, bn = blockIdx.x * 64;

    const short* ap = A + (size_t)(bm + w * 16 + lq) * DIM + lg * 8;
    const short* wp = Wt + (size_t)(bn + lq) * DIM + lg * 8;

    f32x4 acc[4];
#pragma unroll
    for (int nt = 0; nt < 4; nt++) acc[nt] = (f32x4){0.f, 0.f, 0.f, 0.f};
#pragma unroll
    for (int k0 = 0; k0 < DIM; k0 += 32) {
        bf16x8 af = *(const bf16x8*)(ap + k0);
#pragma unroll
        for (int nt = 0; nt < 4; nt++) {
            bf16x8 bfr = *(const bf16x8*)(wp + (size_t)nt * 16 * DIM + k0);
            acc[nt] = __builtin_amdgcn_mfma_f32_16x16x32_bf16(af, bfr, acc[nt], 0, 0, 0);
        }
    }

    int ms = bm + w * 16 + lg * 4;
#pragma unroll
    for (int nt = 0; nt < 4; nt++) {
        int col = bn + nt * 16 + lq;
        float bv_ = bias[col];
        float v[4];
#pragma unroll
        for (int j = 0; j < 4; j++) v[j] = acc[nt][j] + bv_;
        if (z < 2) {
            short* out = (z == 0) ? Qb : Kb;
#pragma unroll
            for (int j = 0; j < 4; j++) out[(size_t)(ms + j) * DIM + col] = f2bf(v[j] * scale);
        } else {
            int cc = ms >> 10, kl = ms & 1023;
            bf16x4 pk;
#pragma unroll
            for (int j = 0; j < 4; j++) pk[j] = f2bf(v[j]);
            *(bf16x4*)(Vt + ((size_t)(cc * DIM + col)) * SKL + kl) = pk;
        }
    }
}

// ---------------------------------------------------------------- fused tail (512 thr)
// G = T1b@Wo + bo; x1 = X + LN(G)*ag+ab; y = LN(x1)*fg+fb;
// g1 = mish(y@W1+b1); x2 = g1@W2 + b2 + x1; out = X + LN(x2)*g+b.
// grid (ROWS/16). All phases row-local after the out-proj GEMM.

__global__ __launch_bounds__(512) void fused_tail(
        const short* __restrict__ T1b, const short* __restrict__ Wot,
        const float* __restrict__ bo, const float* __restrict__ Xres,
        const float* __restrict__ ag, const float* __restrict__ ab,
        const float* __restrict__ fg, const float* __restrict__ fb,
        const short* __restrict__ W1t, const float* __restrict__ b1,
        const short* __restrict__ W2t, const float* __restrict__ b2,
        const float* __restrict__ g_, const float* __restrict__ b_,
        float* __restrict__ outf, short* __restrict__ outb) {
    __shared__ float gbuf[16][264];                     // G, then x1 (kept to phase E)
    __shared__ __align__(16) short y_lds[16][280];      // y bf16 (stride 280: 16B-mult, 2-way banks)
    __shared__ __align__(16) short g1[16][792];         // mish out bf16 (stride 792)
    float (*xbuf)[264] = (float(*)[264])g1;             // x2 fp32, aliases g1 after phase D

    int t = threadIdx.x, l = t & 63, w = t >> 6;        // w: 0..7
    int lq = l & 15, lg = l >> 4;
    int bm = blockIdx.x * 16;

    // ---- phase A: out-proj, wave w -> cols [32w, 32w+32)
    {
        const short* ap = T1b + (size_t)(bm + lq) * DIM + lg * 8;
        const short* wp = Wot + (size_t)(w * 32 + lq) * DIM + lg * 8;
        f32x4 acc[2];
        acc[0] = (f32x4){0.f, 0.f, 0.f, 0.f};
        acc[1] = (f32x4){0.f, 0.f, 0.f, 0.f};
#pragma unroll
        for (int k0 = 0; k0 < DIM; k0 += 32) {
            bf16x8 af = *(const bf16x8*)(ap + k0);
#pragma unroll
            for (int nt = 0; nt < 2; nt++) {
                bf16x8 bfr = *(const bf16x8*)(wp + (size_t)nt * 16 * DIM + k0);
                acc[nt] = __builtin_amdgcn_mfma_f32_16x16x32_bf16(af, bfr, acc[nt], 0, 0, 0);
            }
        }
#pragma unroll
        for (int nt = 0; nt < 2; nt++) {
            int col = w * 32 + nt * 16 + lq;
            float bv_ = bo[col];
#pragma unroll
            for (int j = 0; j < 4; j++) gbuf[lg * 4 + j][col] = acc[nt][j] + bv_;
        }
    }
    __syncthreads();

    // ---- phase B: LN(G)+res -> x1 (in-place in gbuf); LN(x1) -> y_lds bf16
    {
        int g = t >> 5, u = t & 31;
        int row = bm + g;
        float s = 0.f, s2 = 0.f;
#pragma unroll
        for (int i = 0; i < 8; i++) {
            float v = gbuf[g][u + 32 * i];
            s += v; s2 += v * v;
        }
#pragma unroll
        for (int off = 1; off < 32; off <<= 1) { s += __shfl_xor(s, off); s2 += __shfl_xor(s2, off); }
        float m = s * (1.f / DIM);
        float rstd = rsqrtf(s2 * (1.f / DIM) - m * m + 1e-5f);

        float x1v[8];
        float sb = 0.f, sb2 = 0.f;
#pragma unroll
        for (int i = 0; i < 8; i++) {
            int col = u + 32 * i;
            float x1 = Xres[(size_t)row * DIM + col] + (gbuf[g][col] - m) * rstd * ag[col] + ab[col];
            x1v[i] = x1; sb += x1; sb2 += x1 * x1;
        }
#pragma unroll
        for (int off = 1; off < 32; off <<= 1) { sb += __shfl_xor(sb, off); sb2 += __shfl_xor(sb2, off); }
        float m2 = sb * (1.f / DIM);
        float rstd2 = rsqrtf(sb2 * (1.f / DIM) - m2 * m2 + 1e-5f);
#pragma unroll
        for (int i = 0; i < 8; i++) {
            int col = u + 32 * i;
            gbuf[g][col]  = x1v[i];                                   // keep x1
            y_lds[g][col] = f2bf((x1v[i] - m2) * rstd2 * fg[col] + fb[col]);
        }
    }
    __syncthreads();

    // ---- phase C: g1 = mish(y@W1+b1); wave w -> cols [96w, 96w+96)
    {
        const short* wp = W1t + (size_t)(w * 96 + lq) * DIM + lg * 8;
        f32x4 acc[6];
#pragma unroll
        for (int nt = 0; nt < 6; nt++) acc[nt] = (f32x4){0.f, 0.f, 0.f, 0.f};
#pragma unroll
        for (int k0 = 0; k0 < DIM; k0 += 32) {
            bf16x8 af = *(const bf16x8*)(&y_lds[lq][k0 + lg * 8]);
#pragma unroll
            for (int nt = 0; nt < 6; nt++) {
                bf16x8 bfr = *(const bf16x8*)(wp + (size_t)nt * 16 * DIM + k0);
                acc[nt] = __builtin_amdgcn_mfma_f32_16x16x32_bf16(af, bfr, acc[nt], 0, 0, 0);
            }
        }
#pragma unroll
        for (int nt = 0; nt < 6; nt++) {
            int col = w * 96 + nt * 16 + lq;
            float bv_ = b1[col];
#pragma unroll
            for (int j = 0; j < 4; j++)
                g1[lg * 4 + j][col] = f2bf(fast_mish(acc[nt][j] + bv_));
        }
    }
    __syncthreads();

    // ---- phase D: x2 = g1@W2 + b2 + x1; wave w -> cols [32w, 32w+32)
    f32x4 acc2[2];
    acc2[0] = (f32x4){0.f, 0.f, 0.f, 0.f};
    acc2[1] = (f32x4){0.f, 0.f, 0.f, 0.f};
    {
        const short* wp2 = W2t + (size_t)(w * 32 + lq) * FFD + lg * 8;
#pragma unroll 6
        for (int ks = 0; ks < 24; ks++) {
            bf16x8 af = *(const bf16x8*)(&g1[lq][ks * 32 + lg * 8]);
#pragma unroll
            for (int nt = 0; nt < 2; nt++) {
                bf16x8 bfr = *(const bf16x8*)(wp2 + (size_t)nt * 16 * FFD + ks * 32);
                acc2[nt] = __builtin_amdgcn_mfma_f32_16x16x32_bf16(af, bfr, acc2[nt], 0, 0, 0);
            }
        }
    }
    __syncthreads();   // all g1 reads done; xbuf may alias now
#pragma unroll
    for (int nt = 0; nt < 2; nt++) {
        int col = w * 32 + nt * 16 + lq;
        float bv_ = b2[col];
#pragma unroll
        for (int j = 0; j < 4; j++)
            xbuf[lg * 4 + j][col] = acc2[nt][j] + bv_ + gbuf[lg * 4 + j][col];
    }
    __syncthreads();

    // ---- phase E: out = X + LN(x2)*g+b
    {
        int g = t >> 5, u = t & 31;
        int row = bm + g;
        float s = 0.f, s2 = 0.f;
#pragma unroll
        for (int i = 0; i < 8; i++) {
            float v = xbuf[g][u + 32 * i];
            s += v; s2 += v * v;
        }
#pragma unroll
        for (int off = 1; off < 32; off <<= 1) { s += __shfl_xor(s, off); s2 += __shfl_xor(s2, off); }
        float m = s * (1.f / DIM);
        float rstd = rsqrtf(s2 * (1.f / DIM) - m * m + 1e-5f);
#pragma unroll
        for (int i = 0; i < 8; i++) {
            int col = u + 32 * i;
            float o = Xres[(size_t)row * DIM + col] + (xbuf[g][col] - m) * rstd * g_[col] + b_[col];
            outf[(size_t)row * DIM + col] = o;
            if (outb) outb[(size_t)row * DIM + col] = f2bf(o);
        }
    }
}

// ---------------------------------------------------------------- attention
// MFMA QK^T/PV + packed Michelot entmax-1.5 with early exit.
// __launch_bounds__(256,4): allow up to ~128 VGPR so acc[16] f32x4 never spills.
// grid (SQL/16, NH, CB), 256 threads = 4 waves; wave w owns k in [256w, 256w+256).

__global__ __launch_bounds__(256, 4) void attn_mfma(
        const short* __restrict__ Q, const short* __restrict__ K,
        const short* __restrict__ Vt, short* __restrict__ O) {
    int h = blockIdx.y, c = blockIdx.z;
    int qbase = blockIdx.x * 16;
    int t = threadIdx.x, l = t & 63, w = t >> 6;
    int lq = l & 15, lg = l >> 4;

    __shared__ __align__(16) short p_lds[4][1024];     // wave-private [16 q][64 k] chunk
    __shared__ float obuf[4][512];                     // per-wave O partials [q][d]
    __shared__ float redf[2][3][4][16];                // double-buffered reductions

    bf16x8 qfrag = *(const bf16x8*)(Q + ((size_t)(c * SQL + qbase + lq)) * DIM + h * HDIM + lg * 8);

    // ---- QK^T: acc[kt][j] = S[k = 256w+16kt+4lg+j][q=lq]
    const int kw = w * 256;
    f32x4 acc[16];
#pragma unroll
    for (int kt = 0; kt < 16; kt++) {
        bf16x8 kf = *(const bf16x8*)(K + ((size_t)(c * SKL + kw + kt * 16 + lq)) * DIM + h * HDIM + lg * 8);
        f32x4 z = {0.f, 0.f, 0.f, 0.f};
        acc[kt] = __builtin_amdgcn_mfma_f32_16x16x32_bf16(kf, qfrag, z, 0, 0, 0);
    }

    const f32x2 z2  = {0.f, 0.f};
    const f32x2 big = {1e30f, 1e30f};
    const f32x2 one = {1.f, 1.f};

    // ---- row max
    f32x2 mm = lo2(acc[0]);
#pragma unroll
    for (int kt = 0; kt < 16; kt++) {
        mm = __builtin_elementwise_max(mm, lo2(acc[kt]));
        mm = __builtin_elementwise_max(mm, hi2(acc[kt]));
    }
    float m = fmaxf(mm.x, mm.y);
    m = fmaxf(m, __shfl_xor(m, 16));
    m = fmaxf(m, __shfl_xor(m, 32));
    if (l < 16) redf[1][0][w][l] = m;
    __syncthreads();
    m = fmaxf(fmaxf(redf[1][0][0][lq], redf[1][0][1][lq]),
              fmaxf(redf[1][0][2][lq], redf[1][0][3][lq]));

    // ---- Michelot from below: tau0 = m-1; exact quadratic per round; early exit.
    float tau = m - 1.0f;
    int r = 0;
    for (;;) {
        f32x2 vt = {tau, tau};
        f32x2 S1 = z2, S2 = z2, NN = z2;
#pragma unroll
        for (int kt = 0; kt < 16; kt++) {
            f32x2 y0 = __builtin_elementwise_max(lo2(acc[kt]) - vt, z2);
            f32x2 y1 = __builtin_elementwise_max(hi2(acc[kt]) - vt, z2);
            S1 += y0; S1 += y1;
            S2 += y0 * y0; S2 += y1 * y1;
            NN += __builtin_elementwise_min(y0 * big, one);
            NN += __builtin_elementwise_min(y1 * big, one);
        }
        float sy = S1.x + S1.y, sy2 = S2.x + S2.y, nn = NN.x + NN.y;
        sy  += __shfl_xor(sy, 16);  sy  += __shfl_xor(sy, 32);
        sy2 += __shfl_xor(sy2, 16); sy2 += __shfl_xor(sy2, 32);
        nn  += __shfl_xor(nn, 16);  nn  += __shfl_xor(nn, 32);
        int b = r & 1;
        if (l < 16) { redf[b][0][w][l] = nn; redf[b][1][w][l] = sy; redf[b][2][w][l] = sy2; }
        __syncthreads();
        nn  = redf[b][0][0][lq] + redf[b][0][1][lq] + redf[b][0][2][lq] + redf[b][0][3][lq];
        sy  = redf[b][1][0][lq] + redf[b][1][1][lq] + redf[b][1][2][lq] + redf[b][1][3][lq];
        sy2 = redf[b][2][0][lq] + redf[b][2][1][lq] + redf[b][2][2][lq] + redf[b][2][3][lq];
        float disc = fmaxf(sy * sy - nn * (sy2 - 1.0f), 0.f);
        float delta = (sy - sqrtf(disc)) / nn;
        tau = fminf(tau + delta, m - 0.03125f);
        r++;
        if (r >= 6 || __all(delta < 1e-6f)) break;
    }

    // ---- PV in 4 chunks: p -> wave-private swizzled LDS -> MFMA (no barriers)
    f32x4 o0 = {0.f, 0.f, 0.f, 0.f}, o1 = {0.f, 0.f, 0.f, 0.f};
    const short* vbase0 = Vt + ((size_t)(c * DIM + h * HDIM + lq)) * SKL;
    const short* vbase1 = vbase0 + (size_t)16 * SKL;
    {
        f32x2 vt = {tau, tau};
        int swz = (lq & 7) << 4;
#pragma unroll
        for (int c2 = 0; c2 < 4; c2++) {
#pragma unroll
            for (int k4 = 0; k4 < 4; k4++) {
                int kt = c2 * 4 + k4;
                f32x2 y0 = __builtin_elementwise_max(lo2(acc[kt]) - vt, z2);
                f32x2 y1 = __builtin_elementwise_max(hi2(acc[kt]) - vt, z2);
                f32x2 p0 = y0 * y0, p1 = y1 * y1;
                unsigned u01, u23;
                asm("v_cvt_pk_bf16_f32 %0, %1, %2" : "=v"(u01) : "v"(p0.x), "v"(p0.y));
                asm("v_cvt_pk_bf16_f32 %0, %1, %2" : "=v"(u23) : "v"(p1.x), "v"(p1.y));
                int klocal = k4 * 16 + lg * 4;
                int byte = lq * 128 + ((klocal * 2) ^ swz);
                *(uint2*)((char*)p_lds[w] + byte) = make_uint2(u01, u23);
            }
#pragma unroll
            for (int k2 = 0; k2 < 2; k2++) {
                int klocal0 = k2 * 32 + lg * 8;
                int byte = lq * 128 + ((klocal0 * 2) ^ swz);
                bf16x8 pa = *(const bf16x8*)((const char*)p_lds[w] + byte);
                int k0 = kw + c2 * 64 + klocal0;
                bf16x8 vb0 = *(const bf16x8*)(vbase0 + k0);
                bf16x8 vb1 = *(const bf16x8*)(vbase1 + k0);
                o0 = __builtin_amdgcn_mfma_f32_16x16x32_bf16(pa, vb0, o0, 0, 0, 0);
                o1 = __builtin_amdgcn_mfma_f32_16x16x32_bf16(pa, vb1, o1, 0, 0, 0);
            }
        }
    }

    // ---- cross-wave O reduce
#pragma unroll
    for (int j = 0; j < 4; j++) {
        obuf[w][(lg * 4 + j) * 32 + lq]      = o0[j];
        obuf[w][(lg * 4 + j) * 32 + 16 + lq] = o1[j];
    }
    __syncthreads();
#pragma unroll
    for (int rep = 0; rep < 2; rep++) {
        int e = t + rep * 256;
        int q = e >> 5, d = e & 31;
        float s = obuf[0][e] + obuf[1][e] + obuf[2][e] + obuf[3][e];
        O[((size_t)(c * SQL + qbase + q)) * DIM + h * HDIM + d] = f2bf(s);
    }
}

// ---------------------------------------------------------------- driver

extern "C" void kernel_launch(void* const* d_in, const int* in_sizes, int n_in,
                              void* d_out, int out_size, void* d_ws, size_t ws_size,
                              hipStream_t stream) {
    const float* pose = (const float*)d_in[0];
    const float* vel  = (const float*)d_in[1];
    const float* img  = (const float*)d_in[2];
    const float* Wq   = (const float*)d_in[3];
    const float* bq   = (const float*)d_in[4];
    const float* Wk   = (const float*)d_in[5];
    const float* bk   = (const float*)d_in[6];
    const float* Wv   = (const float*)d_in[7];
    const float* bv   = (const float*)d_in[8];
    const float* Wo   = (const float*)d_in[9];
    const float* bo   = (const float*)d_in[10];
    const float* an_g = (const float*)d_in[11];
    const float* an_b = (const float*)d_in[12];
    const float* W1   = (const float*)d_in[13];
    const float* b1   = (const float*)d_in[14];
    const float* W2   = (const float*)d_in[15];
    const float* b2   = (const float*)d_in[16];
    const float* fn_g = (const float*)d_in[17];
    const float* fn_b = (const float*)d_in[18];
    const float* n_g  = (const float*)d_in[19];
    const float* n_b  = (const float*)d_in[20];

    const size_t SZ = (size_t)ROWS * DIM;           // 1M elements
    float* X    = (float*)d_ws;                     // fp32 residual stream
    short* Xb   = (short*)(X + SZ);
    short* KVb  = Xb + SZ;
    short* T1b  = KVb + SZ;                         // attn out bf16
    short* Qb   = T1b + SZ;
    short* Kb   = Qb + SZ;
    short* Vt   = Kb + SZ;                          // [CB][DIM][SKL]
    short* Wqt  = Vt + SZ;
    short* Wkt  = Wqt + (size_t)NL * DIM * DIM;
    short* Wvt  = Wkt + (size_t)NL * DIM * DIM;
    short* Wot  = Wvt + (size_t)NL * DIM * DIM;
    short* W1t  = Wot + (size_t)NL * DIM * DIM;     // [L][768][256]
    short* W2t  = W1t + (size_t)NL * DIM * FFD;     // [L][256][768]

    {
        int total = CB * SQL * DIM;
        init_kernel<<<(total + 255) / 256, 256, 0, stream>>>(pose, vel, img, X, Xb, KVb);
    }
    transpose_all<<<640, 256, 0, stream>>>(Wq, Wk, Wv, Wo, W1, W2,
                                           Wqt, Wkt, Wvt, Wot, W1t, W2t);

    const float qscale = 0.08838834764831845f;      // 0.5 / sqrt(32)

    for (int i = 0; i < NL; i++) {
        const short* Wqt_i = Wqt + (size_t)i * DIM * DIM;
        const short* Wkt_i = Wkt + (size_t)i * DIM * DIM;
        const short* Wvt_i = Wvt + (size_t)i * DIM * DIM;
        const short* Wot_i = Wot + (size_t)i * DIM * DIM;
        const short* W1t_i = W1t + (size_t)i * DIM * FFD;
        const short* W2t_i = W2t + (size_t)i * DIM * FFD;

        qkv_gemm<<<dim3(DIM / 64, ROWS / 64, 3), 256, 0, stream>>>(
            Xb, KVb, Wqt_i, Wkt_i, Wvt_i,
            bq + i * DIM, bk + i * DIM, bv + i * DIM, Qb, Kb, Vt, qscale);

        attn_mfma<<<dim3(SQL / 16, NH, CB), 256, 0, stream>>>(Qb, Kb, Vt, T1b);

        float* outp  = (i == NL - 1) ? (float*)d_out : X;
        short* outbp = (i == NL - 1) ? nullptr : Xb;
        fused_tail<<<ROWS / 16, 512, 0, stream>>>(
            T1b, Wot_i, bo + i * DIM, X,
            an_g + i * DIM, an_b + i * DIM, fn_g + i * DIM, fn_b + i * DIM,
            W1t_i, b1 + i * FFD, W2t_i, b2 + i * DIM,
            n_g + i * DIM, n_b + i * DIM, outp, outbp);
    }

    (void)in_sizes; (void)n_in; (void)out_size; (void)ws_size;
}